// Round 1
// baseline (4669.287 us; speedup 1.0000x reference)
//
#include <hip/hip_runtime.h>
#include <math.h>

namespace {

constexpr int Bn = 1024;   // batch
constexpr int Rn = 512;    // rnn size
constexpr int An = 196;    // att size (== S)
constexpr int Gn = 8192;   // P * 4R
constexpr int CHUNK_B = 128;
constexpr int CHUNK_ROWS = CHUNK_B * An;  // 25088

__device__ __forceinline__ float sigmf(float x) { return 1.0f / (1.0f + __expf(-x)); }

// C[M,N] = (init ? bias[n] : C[m,n]) + A[M,K] * B[N,K]^T
// A row-major [M,K] (lda=K), Bm row-major [N,K] (ldb=K), C ld = ldc.
// M must be a multiple of 128. N may be ragged (guarded).
__global__ __launch_bounds__(256)
void gemm_f32(const float* __restrict__ A, const float* __restrict__ Bm,
              const float* __restrict__ bias, float* __restrict__ C,
              int M, int N, int K, int ldc, int initMode)
{
  __shared__ float As[16][132];
  __shared__ float Bs[16][132];
  const int tid  = threadIdx.x;
  const int row0 = blockIdx.y * 128;
  const int col0 = blockIdx.x * 128;
  const int tx = tid & 15;
  const int ty = tid >> 4;
  float acc[8][8];
#pragma unroll
  for (int i = 0; i < 8; ++i)
#pragma unroll
    for (int j = 0; j < 8; ++j) acc[i][j] = 0.f;

  const int lr = tid >> 1;          // 0..127
  const int lk = (tid & 1) * 8;     // 0 / 8

  for (int kt = 0; kt < K; kt += 16) {
    {
      const float* ap = A + (size_t)(row0 + lr) * K + kt + lk;
      float4 v0 = *(const float4*)ap;
      float4 v1 = *(const float4*)(ap + 4);
      As[lk + 0][lr] = v0.x; As[lk + 1][lr] = v0.y;
      As[lk + 2][lr] = v0.z; As[lk + 3][lr] = v0.w;
      As[lk + 4][lr] = v1.x; As[lk + 5][lr] = v1.y;
      As[lk + 6][lr] = v1.z; As[lk + 7][lr] = v1.w;
    }
    {
      const int gc = col0 + lr;
      float4 v0 = make_float4(0.f, 0.f, 0.f, 0.f);
      float4 v1 = v0;
      if (gc < N) {
        const float* bp = Bm + (size_t)gc * K + kt + lk;
        v0 = *(const float4*)bp;
        v1 = *(const float4*)(bp + 4);
      }
      Bs[lk + 0][lr] = v0.x; Bs[lk + 1][lr] = v0.y;
      Bs[lk + 2][lr] = v0.z; Bs[lk + 3][lr] = v0.w;
      Bs[lk + 4][lr] = v1.x; Bs[lk + 5][lr] = v1.y;
      Bs[lk + 6][lr] = v1.z; Bs[lk + 7][lr] = v1.w;
    }
    __syncthreads();
#pragma unroll
    for (int k = 0; k < 16; ++k) {
      float a0[8], b0[8];
      *(float4*)&a0[0] = *(const float4*)&As[k][ty * 8];
      *(float4*)&a0[4] = *(const float4*)&As[k][ty * 8 + 4];
      *(float4*)&b0[0] = *(const float4*)&Bs[k][tx * 8];
      *(float4*)&b0[4] = *(const float4*)&Bs[k][tx * 8 + 4];
#pragma unroll
      for (int i = 0; i < 8; ++i)
#pragma unroll
        for (int j = 0; j < 8; ++j)
          acc[i][j] = fmaf(a0[i], b0[j], acc[i][j]);
    }
    __syncthreads();
  }

#pragma unroll
  for (int i = 0; i < 8; ++i) {
    const int m = row0 + ty * 8 + i;
#pragma unroll
    for (int j = 0; j < 8; ++j) {
      const int n = col0 + tx * 8 + j;
      if (n < N) {
        const size_t idx = (size_t)m * ldc + n;
        const float base = initMode ? bias[n] : C[idx];
        C[idx] = base + acc[i][j];
      }
    }
  }
}

// score[b,s] = sum_a Wd[a]*tanh(av[row,a] + ah[b,s]) + bd   (note ah indexed by s!)
// av rows are (b-b0)*196+s for the current chunk.
__global__ __launch_bounds__(256)
void score_reduce(const float* __restrict__ av,
                  const float* __restrict__ ah0, const float* __restrict__ ah1,
                  const float* __restrict__ Wd, const float* __restrict__ bd,
                  float* __restrict__ s0, float* __restrict__ s1, int b0)
{
  const int row = blockIdx.x;
  const int t = threadIdx.x;
  const int s = row % An;
  const int b = b0 + row / An;
  const int srow = b * An + s;
  const bool dual = (s1 != nullptr);
  float v0 = 0.f, v1 = 0.f;
  if (t < An) {
    const float a = av[(size_t)row * An + t];
    const float wd = Wd[t];
    v0 = wd * tanhf(a + ah0[srow]);
    if (dual) v1 = wd * tanhf(a + ah1[srow]);
  }
#pragma unroll
  for (int o = 32; o > 0; o >>= 1) {
    v0 += __shfl_down(v0, o);
    v1 += __shfl_down(v1, o);
  }
  __shared__ float r0s[4], r1s[4];
  const int wid = t >> 6;
  if ((t & 63) == 0) { r0s[wid] = v0; r1s[wid] = v1; }
  __syncthreads();
  if (t == 0) {
    s0[srow] = r0s[0] + r0s[1] + r0s[2] + r0s[3] + bd[0];
    if (dual) s1[srow] = r1s[0] + r1s[1] + r1s[2] + r1s[3] + bd[0];
  }
}

__global__ __launch_bounds__(256)
void softmax_rows(float* __restrict__ sc)
{
  const int b = blockIdx.x;
  const int t = threadIdx.x;
  float x = (t < An) ? sc[(size_t)b * An + t] : -3.0e38f;
  float m = x;
#pragma unroll
  for (int o = 32; o > 0; o >>= 1) m = fmaxf(m, __shfl_down(m, o));
  __shared__ float red[4];
  __shared__ float bmax, bsumv;
  const int wid = t >> 6;
  if ((t & 63) == 0) red[wid] = m;
  __syncthreads();
  if (t == 0) bmax = fmaxf(fmaxf(red[0], red[1]), fmaxf(red[2], red[3]));
  __syncthreads();
  float e = (t < An) ? __expf(x - bmax) : 0.f;
  float sm = e;
#pragma unroll
  for (int o = 32; o > 0; o >>= 1) sm += __shfl_down(sm, o);
  if ((t & 63) == 0) red[wid] = sm;
  __syncthreads();
  if (t == 0) bsumv = red[0] + red[1] + red[2] + red[3];
  __syncthreads();
  if (t < An) sc[(size_t)b * An + t] = e / bsumv;
}

// o0[b,r] = sum_s att[b,s,r]*w0[b,s] (+add0[b,r]); optionally o1 with w1 in same att pass.
__global__ __launch_bounds__(256)
void wsum(const float* __restrict__ att,
          const float* __restrict__ w0, const float* __restrict__ w1,
          const float* __restrict__ add0, float* __restrict__ o0, float* __restrict__ o1)
{
  const int b = blockIdx.x;
  const int t = threadIdx.x;
  const int r = blockIdx.y * 256 + t;
  __shared__ float ws0[An], ws1[An];
  if (t < An) {
    ws0[t] = w0[(size_t)b * An + t];
    if (w1) ws1[t] = w1[(size_t)b * An + t];
  }
  __syncthreads();
  const float* ap = att + (size_t)b * An * Rn + r;
  float a0 = 0.f, a1 = 0.f;
  if (w1) {
    for (int s = 0; s < An; ++s) {
      const float v = ap[(size_t)s * Rn];
      a0 = fmaf(v, ws0[s], a0);
      a1 = fmaf(v, ws1[s], a1);
    }
  } else {
    for (int s = 0; s < An; ++s) {
      const float v = ap[(size_t)s * Rn];
      a0 = fmaf(v, ws0[s], a0);
    }
  }
  if (add0) a0 += add0[(size_t)b * Rn + r];
  o0[(size_t)b * Rn + r] = a0;
  if (o1) o1[(size_t)b * Rn + r] = a1;
}

// sums[b, p*2048+g]: [0:512)=ig [512:1024)=fg [1024:1536)=og [1536:2048)=it
__global__ __launch_bounds__(256)
void gates_pw(const float* __restrict__ sums, const float* __restrict__ prev_c,
              float* __restrict__ out_c, float* __restrict__ nh)
{
  const int i = blockIdx.x * 256 + threadIdx.x;   // < Bn*Rn
  const int b = i >> 9;
  const int r = i & 511;
  const float c = prev_c[i];
  float aC = 0.f, aH = 0.f;
#pragma unroll
  for (int p = 0; p < 4; ++p) {
    const float* sp = sums + (size_t)b * Gn + p * 2048 + r;
    const float ig = sigmf(sp[0]);
    const float fg = sigmf(sp[512]);
    const float og = sigmf(sp[1024]);
    const float it = tanhf(sp[1536]);
    const float nc = fmaf(fg, c, ig * it);
    aC += nc;
    aH = fmaf(og, tanhf(nc), aH);
  }
  out_c[i] = aC * 0.25f;
  nh[i] = aH * 0.25f;
}

__global__ void vadd(const float* __restrict__ a, const float* __restrict__ bp,
                     float* __restrict__ o, int n)
{
  const int i = blockIdx.x * 256 + threadIdx.x;
  if (i < n) o[i] = a[i] + bp[i];
}

__global__ void bias3(const float* __restrict__ a, const float* __restrict__ b,
                      const float* __restrict__ c, float* __restrict__ o, int n)
{
  const int i = blockIdx.x * 256 + threadIdx.x;
  if (i < n) o[i] = a[i] + b[i] + c[i];
}

} // namespace

extern "C" void kernel_launch(void* const* d_in, const int* in_sizes, int n_in,
                              void* d_out, int out_size, void* d_ws, size_t ws_size,
                              hipStream_t stream)
{
  const float* x      = (const float*)d_in[0];
  const float* att    = (const float*)d_in[1];
  const float* inputs = (const float*)d_in[2];
  const float* Wa2a   = (const float*)d_in[3];
  const float* ba2a   = (const float*)d_in[4];
  const float* Wh2a   = (const float*)d_in[5];
  const float* bh2a   = (const float*)d_in[6];
  const float* Wd2d   = (const float*)d_in[7];
  const float* bd2d   = (const float*)d_in[8];
  const float* Wa2a1  = (const float*)d_in[9];
  const float* ba2a1  = (const float*)d_in[10];
  const float* Wh2a1  = (const float*)d_in[11];
  const float* bh2a1  = (const float*)d_in[12];
  const float* Wd2d1  = (const float*)d_in[13];
  const float* bd2d1  = (const float*)d_in[14];
  const float* Wi2h   = (const float*)d_in[15];
  const float* bi2h   = (const float*)d_in[16];
  const float* Wh2h   = (const float*)d_in[17];
  const float* bh2h   = (const float*)d_in[18];
  const float* Wa2h   = (const float*)d_in[19];
  const float* ba2h   = (const float*)d_in[20];

  float* out = (float*)d_out;
  const float* prev_c0 = inputs + 0 * (size_t)Bn * Rn;
  const float* prev_h0 = inputs + 1 * (size_t)Bn * Rn;
  const float* prev_c1 = inputs + 2 * (size_t)Bn * Rn;
  const float* prev_h1 = inputs + 3 * (size_t)Bn * Rn;

  float* wsp = (float*)d_ws;
  size_t off = 0;
  auto alloc = [&](size_t nelem) {
    float* p = wsp + off;
    off += (nelem + 255) & ~(size_t)255;
    return p;
  };
  float* ahA  = alloc((size_t)Bn * An);
  float* ahB  = alloc((size_t)Bn * An);
  float* ah1  = alloc((size_t)Bn * An);
  float* scA  = alloc((size_t)Bn * An);
  float* scB  = alloc((size_t)Bn * An);
  float* sc1  = alloc((size_t)Bn * An);
  float* res0 = alloc((size_t)Bn * Rn);
  float* res1 = alloc((size_t)Bn * Rn);
  float* nh   = alloc((size_t)Bn * Rn);
  float* xt   = alloc((size_t)Bn * Rn);
  float* bsum = alloc(Gn);
  float* sums = alloc((size_t)Bn * Gn);
  float* avb  = alloc((size_t)CHUNK_ROWS * An);
  (void)ws_size; (void)in_sizes; (void)n_in; (void)out_size;  // total ~67 MB of ws used

  const dim3 blk(256);
  auto GEMM = [&](const float* A, const float* Bm, const float* bias, float* C,
                  int M, int N, int K, int ldc, int init) {
    dim3 grid((N + 127) / 128, M / 128);
    hipLaunchKernelGGL(gemm_f32, grid, blk, 0, stream, A, Bm, bias, C, M, N, K, ldc, init);
  };

  // combined gate bias: bsum[n] = bi2h[n] + bh2h[n] + ba2h[n]
  hipLaunchKernelGGL(bias3, dim3((Gn + 255) / 256), blk, 0, stream, bi2h, bh2h, ba2h, bsum, Gn);

  // ---- shared first attends (set-0 weights; h known for both layers): one av pass, two scores
  GEMM(prev_h0, Wh2a, bh2a, ahA, Bn, An, Rn, An, 1);
  GEMM(prev_h1, Wh2a, bh2a, ahB, Bn, An, Rn, An, 1);
  for (int c = 0; c < Bn / CHUNK_B; ++c) {
    GEMM(att + (size_t)c * CHUNK_ROWS * Rn, Wa2a, ba2a, avb, CHUNK_ROWS, An, Rn, An, 1);
    hipLaunchKernelGGL(score_reduce, dim3(CHUNK_ROWS), blk, 0, stream,
                       avb, ahA, ahB, Wd2d, bd2d, scA, scB, c * CHUNK_B);
  }
  hipLaunchKernelGGL(softmax_rows, dim3(Bn), blk, 0, stream, scA);
  hipLaunchKernelGGL(softmax_rows, dim3(Bn), blk, 0, stream, scB);
  hipLaunchKernelGGL(wsum, dim3(Bn, Rn / 256), blk, 0, stream,
                     att, scA, scB, (const float*)nullptr, res0, res1);

  // ---- layer 0 LSTM (xt = x)
  GEMM(x,       Wi2h, bsum,    sums, Bn, Gn, Rn, Gn, 1);
  GEMM(prev_h0, Wh2h, nullptr, sums, Bn, Gn, Rn, Gn, 0);
  GEMM(res0,    Wa2h, nullptr, sums, Bn, Gn, Rn, Gn, 0);
  hipLaunchKernelGGL(gates_pw, dim3(Bn * Rn / 256), blk, 0, stream, sums, prev_c0, out + 0, nh);

  // ---- layer 0 second attend -> top_h0 = attres1 + next_h0
  GEMM(nh, Wh2a1, bh2a1, ah1, Bn, An, Rn, An, 1);
  for (int c = 0; c < Bn / CHUNK_B; ++c) {
    GEMM(att + (size_t)c * CHUNK_ROWS * Rn, Wa2a1, ba2a1, avb, CHUNK_ROWS, An, Rn, An, 1);
    hipLaunchKernelGGL(score_reduce, dim3(CHUNK_ROWS), blk, 0, stream,
                       avb, ah1, (const float*)nullptr, Wd2d1, bd2d1, sc1, (float*)nullptr, c * CHUNK_B);
  }
  hipLaunchKernelGGL(softmax_rows, dim3(Bn), blk, 0, stream, sc1);
  hipLaunchKernelGGL(wsum, dim3(Bn, Rn / 256), blk, 0, stream,
                     att, sc1, (const float*)nullptr, nh, out + (size_t)Bn * Rn, (float*)nullptr);

  // ---- layer 1 (xt = x + top_h0)
  hipLaunchKernelGGL(vadd, dim3(Bn * Rn / 256), blk, 0, stream, x, out + (size_t)Bn * Rn, xt, Bn * Rn);
  GEMM(xt,      Wi2h, bsum,    sums, Bn, Gn, Rn, Gn, 1);
  GEMM(prev_h1, Wh2h, nullptr, sums, Bn, Gn, Rn, Gn, 0);
  GEMM(res1,    Wa2h, nullptr, sums, Bn, Gn, Rn, Gn, 0);
  hipLaunchKernelGGL(gates_pw, dim3(Bn * Rn / 256), blk, 0, stream, sums, prev_c1, out + 2 * (size_t)Bn * Rn, nh);

  // ---- layer 1 second attend -> top_h1
  GEMM(nh, Wh2a1, bh2a1, ah1, Bn, An, Rn, An, 1);
  for (int c = 0; c < Bn / CHUNK_B; ++c) {
    GEMM(att + (size_t)c * CHUNK_ROWS * Rn, Wa2a1, ba2a1, avb, CHUNK_ROWS, An, Rn, An, 1);
    hipLaunchKernelGGL(score_reduce, dim3(CHUNK_ROWS), blk, 0, stream,
                       avb, ah1, (const float*)nullptr, Wd2d1, bd2d1, sc1, (float*)nullptr, c * CHUNK_B);
  }
  hipLaunchKernelGGL(softmax_rows, dim3(Bn), blk, 0, stream, sc1);
  hipLaunchKernelGGL(wsum, dim3(Bn, Rn / 256), blk, 0, stream,
                     att, sc1, (const float*)nullptr, nh, out + 3 * (size_t)Bn * Rn, (float*)nullptr);
}

// Round 2
// 928.909 us; speedup vs baseline: 5.0266x; 5.0266x over previous
//
#include <hip/hip_runtime.h>
#include <math.h>

typedef __attribute__((ext_vector_type(8))) unsigned short ushort8_t;
typedef __attribute__((ext_vector_type(8))) short bf16x8;
typedef __attribute__((ext_vector_type(4))) float f32x4;

namespace {

constexpr int Bn = 1024;
constexpr int Rn = 512;
constexpr int An = 196;
constexpr int Gn = 8192;     // P*4R
constexpr int Kcat = 1536;   // 3*R
constexpr int CHUNK_B = 256;
constexpr int CHUNK_ROWS = CHUNK_B * An;  // 50176

__device__ __forceinline__ float b2f(unsigned short u) {
  union { unsigned int i; float f; } v; v.i = ((unsigned int)u) << 16; return v.f;
}
__device__ __forceinline__ unsigned short f2b(float f) {
  union { float f; unsigned int i; } v; v.f = f;
  unsigned int r = v.i + 0x7fffu + ((v.i >> 16) & 1u);
  return (unsigned short)(r >> 16);
}
__device__ __forceinline__ float sigmf(float x) { return 1.f / (1.f + __expf(-x)); }

// ---- f32 -> bf16 copy, 8 elems/thread, n % 8 == 0
__global__ __launch_bounds__(256)
void f2b_copy(const float* __restrict__ src, unsigned short* __restrict__ dst, long n)
{
  long i = ((long)blockIdx.x * 256 + threadIdx.x) * 8;
  const long stride = (long)gridDim.x * 256 * 8;
  for (; i + 8 <= n; i += stride) {
    float4 a = *(const float4*)(src + i);
    float4 b = *(const float4*)(src + i + 4);
    ushort8_t o;
    o[0] = f2b(a.x); o[1] = f2b(a.y); o[2] = f2b(a.z); o[3] = f2b(a.w);
    o[4] = f2b(b.x); o[5] = f2b(b.y); o[6] = f2b(b.z); o[7] = f2b(b.w);
    *(ushort8_t*)(dst + i) = o;
  }
}

// ---- concat gate weights [8192][1536] bf16: [Wi | Wh | Wa]
__global__ __launch_bounds__(256)
void pack_w(const float* __restrict__ Wi, const float* __restrict__ Wh,
            const float* __restrict__ Wa, unsigned short* __restrict__ W2)
{
  long i = ((long)blockIdx.x * 256 + threadIdx.x) * 8;
  const long total = (long)Gn * Kcat;
  if (i >= total) return;
  const int g = (int)(i / Kcat);
  const int k = (int)(i % Kcat);
  const float* src = (k < 512) ? Wi + (long)g * 512 + k
                   : (k < 1024) ? Wh + (long)g * 512 + (k - 512)
                   : Wa + (long)g * 512 + (k - 1024);
  float4 a = *(const float4*)src;
  float4 b = *(const float4*)(src + 4);
  ushort8_t o;
  o[0] = f2b(a.x); o[1] = f2b(a.y); o[2] = f2b(a.z); o[3] = f2b(a.w);
  o[4] = f2b(b.x); o[5] = f2b(b.y); o[6] = f2b(b.z); o[7] = f2b(b.w);
  *(ushort8_t*)(W2 + i) = o;
}

// ---- concat gate inputs [1024][1536] bf16: [xa(+xb) | h | a]
__global__ __launch_bounds__(256)
void pack_x(const float* __restrict__ xa, const float* __restrict__ xb,
            const float* __restrict__ h, const float* __restrict__ a,
            unsigned short* __restrict__ X2)
{
  long i = ((long)blockIdx.x * 256 + threadIdx.x) * 8;
  if (i >= (long)Bn * Kcat) return;
  const int b = (int)(i / Kcat);
  const int k = (int)(i % Kcat);
  ushort8_t o;
  if (k < 512) {
    const float* s = xa + (long)b * 512 + k;
    float4 v0 = *(const float4*)s, v1 = *(const float4*)(s + 4);
    if (xb) {
      const float* s2 = xb + (long)b * 512 + k;
      float4 w0 = *(const float4*)s2, w1 = *(const float4*)(s2 + 4);
      v0.x += w0.x; v0.y += w0.y; v0.z += w0.z; v0.w += w0.w;
      v1.x += w1.x; v1.y += w1.y; v1.z += w1.z; v1.w += w1.w;
    }
    o[0] = f2b(v0.x); o[1] = f2b(v0.y); o[2] = f2b(v0.z); o[3] = f2b(v0.w);
    o[4] = f2b(v1.x); o[5] = f2b(v1.y); o[6] = f2b(v1.z); o[7] = f2b(v1.w);
  } else {
    const float* s = (k < 1024) ? h + (long)b * 512 + (k - 512)
                                : a + (long)b * 512 + (k - 1024);
    float4 v0 = *(const float4*)s, v1 = *(const float4*)(s + 4);
    o[0] = f2b(v0.x); o[1] = f2b(v0.y); o[2] = f2b(v0.z); o[3] = f2b(v0.w);
    o[4] = f2b(v1.x); o[5] = f2b(v1.y); o[6] = f2b(v1.z); o[7] = f2b(v1.w);
  }
  *(ushort8_t*)(X2 + i) = o;
}

// ---- bf16 MFMA GEMM: C[M,N] = A[M,K] * B[N,K]^T + bias[n]
// A, B bf16 row-major; C f32 or bf16 (ldc given). M % 128 == 0. N ragged ok.
template<bool OUT_BF16>
__global__ __launch_bounds__(256)
void gemm_bf(const unsigned short* __restrict__ A, const unsigned short* __restrict__ Bm,
             const float* __restrict__ bias, void* __restrict__ Cv,
             int N, int K, int ldc)
{
  constexpr int LDP = 40;  // padded bf16 row stride in LDS
  __shared__ unsigned short As[128 * LDP];
  __shared__ unsigned short Bs[128 * LDP];
  const int tid = threadIdx.x;
  const long row0 = (long)blockIdx.y * 128;
  const int col0 = blockIdx.x * 128;
  const int wid = tid >> 6, lane = tid & 63;
  const int wr = wid >> 1, wc = wid & 1;
  const int fr = lane & 15, kg = (lane >> 4) * 8;

  f32x4 acc[4][4] = {};

  const int srow = tid >> 1;
  const int skh = tid & 1;
  const unsigned short* Ap = A + (row0 + srow) * (long)K + skh * 16;
  const int bcol = col0 + srow;
  const unsigned short* Bp = Bm + (long)(bcol < N ? bcol : N - 1) * K + skh * 16;

  ushort8_t a0 = *(const ushort8_t*)(Ap);
  ushort8_t a1 = *(const ushort8_t*)(Ap + 8);
  ushort8_t b0 = *(const ushort8_t*)(Bp);
  ushort8_t b1 = *(const ushort8_t*)(Bp + 8);

  const int sw = srow * LDP + skh * 16;
  for (int kt = 0; kt < K; kt += 32) {
    *(ushort8_t*)&As[sw] = a0;
    *(ushort8_t*)&As[sw + 8] = a1;
    *(ushort8_t*)&Bs[sw] = b0;
    *(ushort8_t*)&Bs[sw + 8] = b1;
    if (kt + 32 < K) {
      a0 = *(const ushort8_t*)(Ap + kt + 32);
      a1 = *(const ushort8_t*)(Ap + kt + 40);
      b0 = *(const ushort8_t*)(Bp + kt + 32);
      b1 = *(const ushort8_t*)(Bp + kt + 40);
    }
    __syncthreads();
    bf16x8 af[4], bfr[4];
#pragma unroll
    for (int m = 0; m < 4; ++m)
      af[m] = *(const bf16x8*)&As[(wr * 64 + m * 16 + fr) * LDP + kg];
#pragma unroll
    for (int n = 0; n < 4; ++n)
      bfr[n] = *(const bf16x8*)&Bs[(wc * 64 + n * 16 + fr) * LDP + kg];
#pragma unroll
    for (int m = 0; m < 4; ++m)
#pragma unroll
      for (int n = 0; n < 4; ++n)
        acc[m][n] = __builtin_amdgcn_mfma_f32_16x16x32_bf16(af[m], bfr[n], acc[m][n], 0, 0, 0);
    __syncthreads();
  }

  const int crow = wr * 64 + (lane >> 4) * 4;
  const int ccol = wc * 64 + fr;
#pragma unroll
  for (int n = 0; n < 4; ++n) {
    const int col = col0 + ccol + n * 16;
    if (col >= N) continue;
    const float bv = bias ? bias[col] : 0.f;
#pragma unroll
    for (int m = 0; m < 4; ++m) {
      const long rb = row0 + crow + m * 16;
#pragma unroll
      for (int j = 0; j < 4; ++j) {
        const float v = acc[m][n][j] + bv;
        const long idx = (rb + j) * (long)ldc + col;
        if (OUT_BF16) ((unsigned short*)Cv)[idx] = f2b(v);
        else          ((float*)Cv)[idx] = v;
      }
    }
  }
}

// ---- dual score over f32 av chunk: one wave per row
__global__ __launch_bounds__(256)
void score2(const float* __restrict__ av, const float* __restrict__ ah0,
            const float* __restrict__ ah1, const float* __restrict__ Wd,
            const float* __restrict__ bd, float* __restrict__ s0,
            float* __restrict__ s1, int b0)
{
  const int row = blockIdx.x * 4 + (threadIdx.x >> 6);
  const int lane = threadIdx.x & 63;
  const int s = row % An;
  const int b = b0 + row / An;
  const int srow = b * An + s;
  const float* avp = av + (long)row * An;
  const float A0 = ah0[srow], A1 = ah1[srow];
  float v0 = 0.f, v1 = 0.f;
  for (int a = lane; a < An; a += 64) {
    const float w = Wd[a], t = avp[a];
    v0 += w * tanhf(t + A0);
    v1 += w * tanhf(t + A1);
  }
#pragma unroll
  for (int o = 32; o; o >>= 1) { v0 += __shfl_down(v0, o); v1 += __shfl_down(v1, o); }
  if (lane == 0) { s0[srow] = v0 + bd[0]; s1[srow] = v1 + bd[0]; }
}

// ---- single score over cached bf16 av (full size, row == b*An+s)
__global__ __launch_bounds__(256)
void score1(const unsigned short* __restrict__ av, const float* __restrict__ ah,
            const float* __restrict__ Wd, const float* __restrict__ bd,
            float* __restrict__ s0)
{
  const int row = blockIdx.x * 4 + (threadIdx.x >> 6);
  const int lane = threadIdx.x & 63;
  const unsigned short* avp = av + (long)row * An;
  const float A0 = ah[row];
  float v0 = 0.f;
  for (int a = lane; a < An; a += 64)
    v0 += Wd[a] * tanhf(b2f(avp[a]) + A0);
#pragma unroll
  for (int o = 32; o; o >>= 1) v0 += __shfl_down(v0, o);
  if (lane == 0) s0[row] = v0 + bd[0];
}

__global__ __launch_bounds__(256)
void softmax_rows(float* __restrict__ sc)
{
  const int b = blockIdx.x;
  const int t = threadIdx.x;
  float x = (t < An) ? sc[(long)b * An + t] : -3.0e38f;
  float m = x;
#pragma unroll
  for (int o = 32; o > 0; o >>= 1) m = fmaxf(m, __shfl_down(m, o));
  __shared__ float red[4];
  __shared__ float bmax, bsumv;
  const int wid = t >> 6;
  if ((t & 63) == 0) red[wid] = m;
  __syncthreads();
  if (t == 0) bmax = fmaxf(fmaxf(red[0], red[1]), fmaxf(red[2], red[3]));
  __syncthreads();
  float e = (t < An) ? __expf(x - bmax) : 0.f;
  float sm = e;
#pragma unroll
  for (int o = 32; o > 0; o >>= 1) sm += __shfl_down(sm, o);
  if ((t & 63) == 0) red[wid] = sm;
  __syncthreads();
  if (t == 0) bsumv = red[0] + red[1] + red[2] + red[3];
  __syncthreads();
  if (t < An) sc[(long)b * An + t] = e / bsumv;
}

// ---- weighted sum over bf16 att; thread handles 2 r-cols (ushort2)
__global__ __launch_bounds__(256)
void wsum_bf(const unsigned short* __restrict__ att,
             const float* __restrict__ w0, const float* __restrict__ w1,
             const float* __restrict__ add0,
             float* __restrict__ o0, float* __restrict__ o1)
{
  const int b = blockIdx.x;
  const int t = threadIdx.x;
  __shared__ float ws0[An], ws1[An];
  if (t < An) {
    ws0[t] = w0[(long)b * An + t];
    if (w1) ws1[t] = w1[(long)b * An + t];
  }
  __syncthreads();
  const ushort2* ap = (const ushort2*)(att + (long)b * An * Rn) + t;
  float a00 = 0.f, a01 = 0.f, a10 = 0.f, a11 = 0.f;
  if (w1) {
    for (int s = 0; s < An; ++s) {
      ushort2 u = ap[(long)s * 256];
      const float f0 = b2f(u.x), f1 = b2f(u.y);
      a00 = fmaf(f0, ws0[s], a00); a01 = fmaf(f1, ws0[s], a01);
      a10 = fmaf(f0, ws1[s], a10); a11 = fmaf(f1, ws1[s], a11);
    }
  } else {
    for (int s = 0; s < An; ++s) {
      ushort2 u = ap[(long)s * 256];
      a00 = fmaf(b2f(u.x), ws0[s], a00); a01 = fmaf(b2f(u.y), ws0[s], a01);
    }
  }
  const long base = (long)b * Rn + 2 * t;
  if (add0) { a00 += add0[base]; a01 += add0[base + 1]; }
  o0[base] = a00; o0[base + 1] = a01;
  if (o1) { o1[base] = a10; o1[base + 1] = a11; }
}

// ---- LSTM pointwise over P=4 parallels; writes c, h(f32), h(bf16)
__global__ __launch_bounds__(256)
void gates_pw(const float* __restrict__ sums, const float* __restrict__ prev_c,
              float* __restrict__ out_c, float* __restrict__ nh,
              unsigned short* __restrict__ nh_bf)
{
  const int i = blockIdx.x * 256 + threadIdx.x;
  const int b = i >> 9;
  const int r = i & 511;
  const float c = prev_c[i];
  float aC = 0.f, aH = 0.f;
#pragma unroll
  for (int p = 0; p < 4; ++p) {
    const float* sp = sums + (long)b * Gn + p * 2048 + r;
    const float ig = sigmf(sp[0]);
    const float fg = sigmf(sp[512]);
    const float og = sigmf(sp[1024]);
    const float it = tanhf(sp[1536]);
    const float nc = fmaf(fg, c, ig * it);
    aC += nc;
    aH = fmaf(og, tanhf(nc), aH);
  }
  out_c[i] = aC * 0.25f;
  const float hv = aH * 0.25f;
  nh[i] = hv;
  nh_bf[i] = f2b(hv);
}

__global__ __launch_bounds__(256)
void bias3(const float* __restrict__ a, const float* __restrict__ b,
           const float* __restrict__ c, float* __restrict__ o, int n)
{
  const int i = blockIdx.x * 256 + threadIdx.x;
  if (i < n) o[i] = a[i] + b[i] + c[i];
}

} // namespace

extern "C" void kernel_launch(void* const* d_in, const int* in_sizes, int n_in,
                              void* d_out, int out_size, void* d_ws, size_t ws_size,
                              hipStream_t stream)
{
  const float* x      = (const float*)d_in[0];
  const float* att    = (const float*)d_in[1];
  const float* inputs = (const float*)d_in[2];
  const float* Wa2a   = (const float*)d_in[3];
  const float* ba2a   = (const float*)d_in[4];
  const float* Wh2a   = (const float*)d_in[5];
  const float* bh2a   = (const float*)d_in[6];
  const float* Wd2d   = (const float*)d_in[7];
  const float* bd2d   = (const float*)d_in[8];
  const float* Wa2a1  = (const float*)d_in[9];
  const float* ba2a1  = (const float*)d_in[10];
  const float* Wh2a1  = (const float*)d_in[11];
  const float* bh2a1  = (const float*)d_in[12];
  const float* Wd2d1  = (const float*)d_in[13];
  const float* bd2d1  = (const float*)d_in[14];
  const float* Wi2h   = (const float*)d_in[15];
  const float* bi2h   = (const float*)d_in[16];
  const float* Wh2h   = (const float*)d_in[17];
  const float* bh2h   = (const float*)d_in[18];
  const float* Wa2h   = (const float*)d_in[19];
  const float* ba2h   = (const float*)d_in[20];
  (void)in_sizes; (void)n_in; (void)out_size; (void)ws_size;

  float* out = (float*)d_out;
  const float* prev_c0 = inputs + 0 * (long)Bn * Rn;
  const float* prev_h0 = inputs + 1 * (long)Bn * Rn;
  const float* prev_c1 = inputs + 2 * (long)Bn * Rn;
  const float* prev_h1 = inputs + 3 * (long)Bn * Rn;

  char* wsp = (char*)d_ws;
  size_t off = 0;
  auto alloc = [&](size_t bytes) -> void* {
    void* p = wsp + off;
    off += (bytes + 1023) & ~(size_t)1023;
    return p;
  };
  unsigned short* att_bf  = (unsigned short*)alloc((size_t)Bn * An * Rn * 2);
  unsigned short* W2      = (unsigned short*)alloc((size_t)Gn * Kcat * 2);
  unsigned short* wh2a_bf = (unsigned short*)alloc((size_t)An * Rn * 2);
  unsigned short* wa2a_bf = (unsigned short*)alloc((size_t)An * Rn * 2);
  unsigned short* wh2a1_bf= (unsigned short*)alloc((size_t)An * Rn * 2);
  unsigned short* wa2a1_bf= (unsigned short*)alloc((size_t)An * Rn * 2);
  unsigned short* h0_bf   = (unsigned short*)alloc((size_t)Bn * Rn * 2);
  unsigned short* h1_bf   = (unsigned short*)alloc((size_t)Bn * Rn * 2);
  unsigned short* nh_bf   = (unsigned short*)alloc((size_t)Bn * Rn * 2);
  unsigned short* X2      = (unsigned short*)alloc((size_t)Bn * Kcat * 2);
  unsigned short* av1_bf  = (unsigned short*)alloc((size_t)Bn * An * An * 2);
  float* avb  = (float*)alloc((size_t)CHUNK_ROWS * An * 4);
  float* ahA  = (float*)alloc((size_t)Bn * An * 4);
  float* ahB  = (float*)alloc((size_t)Bn * An * 4);
  float* ah1  = (float*)alloc((size_t)Bn * An * 4);
  float* scA  = (float*)alloc((size_t)Bn * An * 4);
  float* scB  = (float*)alloc((size_t)Bn * An * 4);
  float* sc1  = (float*)alloc((size_t)Bn * An * 4);
  float* res0 = (float*)alloc((size_t)Bn * Rn * 4);
  float* res1 = (float*)alloc((size_t)Bn * Rn * 4);
  float* nh   = (float*)alloc((size_t)Bn * Rn * 4);
  float* bsum = (float*)alloc((size_t)Gn * 4);
  float* sums = (float*)alloc((size_t)Bn * Gn * 4);

  const dim3 blk(256);

  // ---- conversions
  f2b_copy<<<dim3(50176), blk, 0, stream>>>(att, att_bf, (long)Bn * An * Rn);
  f2b_copy<<<dim3(49), blk, 0, stream>>>(Wh2a,  wh2a_bf,  (long)An * Rn);
  f2b_copy<<<dim3(49), blk, 0, stream>>>(Wa2a,  wa2a_bf,  (long)An * Rn);
  f2b_copy<<<dim3(49), blk, 0, stream>>>(Wh2a1, wh2a1_bf, (long)An * Rn);
  f2b_copy<<<dim3(49), blk, 0, stream>>>(Wa2a1, wa2a1_bf, (long)An * Rn);
  f2b_copy<<<dim3(256), blk, 0, stream>>>(prev_h0, h0_bf, (long)Bn * Rn);
  f2b_copy<<<dim3(256), blk, 0, stream>>>(prev_h1, h1_bf, (long)Bn * Rn);
  pack_w<<<dim3(6144), blk, 0, stream>>>(Wi2h, Wh2h, Wa2h, W2);
  bias3<<<dim3(Gn / 256), blk, 0, stream>>>(bi2h, bh2h, ba2h, bsum, Gn);

  // ---- ah projections for both layers' first attends
  gemm_bf<false><<<dim3(2, Bn / 128), blk, 0, stream>>>(h0_bf, wh2a_bf, bh2a, ahA, An, Rn, An);
  gemm_bf<false><<<dim3(2, Bn / 128), blk, 0, stream>>>(h1_bf, wh2a_bf, bh2a, ahB, An, Rn, An);

  // ---- av1 (shared by both second attends), cached bf16
  gemm_bf<true><<<dim3(2, (Bn * An) / 128), blk, 0, stream>>>(att_bf, wa2a1_bf, ba2a1, av1_bf, An, Rn, An);

  // ---- first attends: chunked av0 + dual score
  for (int c = 0; c < Bn / CHUNK_B; ++c) {
    gemm_bf<false><<<dim3(2, CHUNK_ROWS / 128), blk, 0, stream>>>(
        att_bf + (long)c * CHUNK_ROWS * Rn, wa2a_bf, ba2a, avb, An, Rn, An);
    score2<<<dim3(CHUNK_ROWS / 4), blk, 0, stream>>>(avb, ahA, ahB, Wd2d, bd2d, scA, scB, c * CHUNK_B);
  }
  softmax_rows<<<dim3(Bn), blk, 0, stream>>>(scA);
  softmax_rows<<<dim3(Bn), blk, 0, stream>>>(scB);
  wsum_bf<<<dim3(Bn), blk, 0, stream>>>(att_bf, scA, scB, (const float*)nullptr, res0, res1);

  // ---- layer 0 LSTM
  pack_x<<<dim3(768), blk, 0, stream>>>(x, (const float*)nullptr, prev_h0, res0, X2);
  gemm_bf<false><<<dim3(Gn / 128, Bn / 128), blk, 0, stream>>>(X2, W2, bsum, sums, Gn, Kcat, Gn);
  gates_pw<<<dim3(Bn * Rn / 256), blk, 0, stream>>>(sums, prev_c0, out + 0, nh, nh_bf);

  // ---- layer 0 second attend -> top_h0
  gemm_bf<false><<<dim3(2, Bn / 128), blk, 0, stream>>>(nh_bf, wh2a1_bf, bh2a1, ah1, An, Rn, An);
  score1<<<dim3((Bn * An) / 4), blk, 0, stream>>>(av1_bf, ah1, Wd2d1, bd2d1, sc1);
  softmax_rows<<<dim3(Bn), blk, 0, stream>>>(sc1);
  wsum_bf<<<dim3(Bn), blk, 0, stream>>>(att_bf, sc1, (const float*)nullptr, nh,
                                        out + (long)Bn * Rn, (float*)nullptr);

  // ---- layer 1 LSTM (xt = x + top_h0)
  pack_x<<<dim3(768), blk, 0, stream>>>(x, out + (long)Bn * Rn, prev_h1, res1, X2);
  gemm_bf<false><<<dim3(Gn / 128, Bn / 128), blk, 0, stream>>>(X2, W2, bsum, sums, Gn, Kcat, Gn);
  gates_pw<<<dim3(Bn * Rn / 256), blk, 0, stream>>>(sums, prev_c1, out + 2 * (long)Bn * Rn, nh, nh_bf);

  // ---- layer 1 second attend -> top_h1
  gemm_bf<false><<<dim3(2, Bn / 128), blk, 0, stream>>>(nh_bf, wh2a1_bf, bh2a1, ah1, An, Rn, An);
  score1<<<dim3((Bn * An) / 4), blk, 0, stream>>>(av1_bf, ah1, Wd2d1, bd2d1, sc1);
  softmax_rows<<<dim3(Bn), blk, 0, stream>>>(sc1);
  wsum_bf<<<dim3(Bn), blk, 0, stream>>>(att_bf, sc1, (const float*)nullptr, nh,
                                        out + 3 * (long)Bn * Rn, (float*)nullptr);
}

// Round 3
// 773.838 us; speedup vs baseline: 6.0339x; 1.2004x over previous
//
#include <hip/hip_runtime.h>
#include <math.h>

typedef __attribute__((ext_vector_type(8))) unsigned short ushort8_t;
typedef __attribute__((ext_vector_type(8))) short bf16x8;
typedef __attribute__((ext_vector_type(4))) float f32x4;

namespace {

constexpr int Bn = 1024;
constexpr int Rn = 512;
constexpr int An = 196;
constexpr int Gn = 8192;     // P*4R
constexpr int Kcat = 1536;   // 3*R
constexpr int NP = 224;      // padded att cols (14 frags)
constexpr long ROWS = (long)Bn * An;  // 200704

__device__ __forceinline__ float b2f(unsigned short u) {
  union { unsigned int i; float f; } v; v.i = ((unsigned int)u) << 16; return v.f;
}
__device__ __forceinline__ unsigned short f2b(float f) {
  union { float f; unsigned int i; } v; v.f = f;
  unsigned int r = v.i + 0x7fffu + ((v.i >> 16) & 1u);
  return (unsigned short)(r >> 16);
}
__device__ __forceinline__ float sigmf(float x) {
  return __builtin_amdgcn_rcpf(1.f + __expf(-x));
}
__device__ __forceinline__ float tanhf_fast(float x) {
  const float e = __expf(2.f * x);
  return 1.f - 2.f * __builtin_amdgcn_rcpf(e + 1.f);
}

// ---- f32 -> bf16 copy, 8 elems/thread
__global__ __launch_bounds__(256)
void f2b_copy(const float* __restrict__ src, unsigned short* __restrict__ dst, long n)
{
  long i = ((long)blockIdx.x * 256 + threadIdx.x) * 8;
  const long stride = (long)gridDim.x * 256 * 8;
  for (; i + 8 <= n; i += stride) {
    float4 a = *(const float4*)(src + i);
    float4 b = *(const float4*)(src + i + 4);
    ushort8_t o;
    o[0] = f2b(a.x); o[1] = f2b(a.y); o[2] = f2b(a.z); o[3] = f2b(a.w);
    o[4] = f2b(b.x); o[5] = f2b(b.y); o[6] = f2b(b.z); o[7] = f2b(b.w);
    *(ushort8_t*)(dst + i) = o;
  }
}

// ---- pad+convert attention weights: Wp[2][NP][512] from Wa0/Wa1 [196][512]
__global__ __launch_bounds__(256)
void pack_wpad(const float* __restrict__ Wa0, const float* __restrict__ Wa1,
               unsigned short* __restrict__ Wp)
{
  long i = ((long)blockIdx.x * 256 + threadIdx.x) * 8;
  if (i >= 2L * NP * 512) return;
  const int set = (int)(i / (NP * 512));
  const int rem = (int)(i % (NP * 512));
  const int row = rem / 512, k = rem % 512;
  ushort8_t o;
  if (row < An) {
    const float* s = (set ? Wa1 : Wa0) + (long)row * 512 + k;
    float4 a = *(const float4*)s, b = *(const float4*)(s + 4);
    o[0] = f2b(a.x); o[1] = f2b(a.y); o[2] = f2b(a.z); o[3] = f2b(a.w);
    o[4] = f2b(b.x); o[5] = f2b(b.y); o[6] = f2b(b.z); o[7] = f2b(b.w);
  } else {
    o = ushort8_t{0,0,0,0,0,0,0,0};
  }
  *(ushort8_t*)(Wp + i) = o;
}

// ---- concat gate weights [8192][1536] bf16: [Wi | Wh | Wa]
__global__ __launch_bounds__(256)
void pack_w(const float* __restrict__ Wi, const float* __restrict__ Wh,
            const float* __restrict__ Wa, unsigned short* __restrict__ W2)
{
  long i = ((long)blockIdx.x * 256 + threadIdx.x) * 8;
  if (i >= (long)Gn * Kcat) return;
  const int g = (int)(i / Kcat);
  const int k = (int)(i % Kcat);
  const float* src = (k < 512) ? Wi + (long)g * 512 + k
                   : (k < 1024) ? Wh + (long)g * 512 + (k - 512)
                   : Wa + (long)g * 512 + (k - 1024);
  float4 a = *(const float4*)src;
  float4 b = *(const float4*)(src + 4);
  ushort8_t o;
  o[0] = f2b(a.x); o[1] = f2b(a.y); o[2] = f2b(a.z); o[3] = f2b(a.w);
  o[4] = f2b(b.x); o[5] = f2b(b.y); o[6] = f2b(b.z); o[7] = f2b(b.w);
  *(ushort8_t*)(W2 + i) = o;
}

// ---- concat gate inputs [1024][1536] bf16: [xa(+xb) | h | a]
__global__ __launch_bounds__(256)
void pack_x(const float* __restrict__ xa, const float* __restrict__ xb,
            const float* __restrict__ h, const float* __restrict__ a,
            unsigned short* __restrict__ X2)
{
  long i = ((long)blockIdx.x * 256 + threadIdx.x) * 8;
  if (i >= (long)Bn * Kcat) return;
  const int b = (int)(i / Kcat);
  const int k = (int)(i % Kcat);
  ushort8_t o;
  if (k < 512) {
    const float* s = xa + (long)b * 512 + k;
    float4 v0 = *(const float4*)s, v1 = *(const float4*)(s + 4);
    if (xb) {
      const float* s2 = xb + (long)b * 512 + k;
      float4 w0 = *(const float4*)s2, w1 = *(const float4*)(s2 + 4);
      v0.x += w0.x; v0.y += w0.y; v0.z += w0.z; v0.w += w0.w;
      v1.x += w1.x; v1.y += w1.y; v1.z += w1.z; v1.w += w1.w;
    }
    o[0] = f2b(v0.x); o[1] = f2b(v0.y); o[2] = f2b(v0.z); o[3] = f2b(v0.w);
    o[4] = f2b(v1.x); o[5] = f2b(v1.y); o[6] = f2b(v1.z); o[7] = f2b(v1.w);
  } else {
    const float* s = (k < 1024) ? h + (long)b * 512 + (k - 512)
                                : a + (long)b * 512 + (k - 1024);
    float4 v0 = *(const float4*)s, v1 = *(const float4*)(s + 4);
    o[0] = f2b(v0.x); o[1] = f2b(v0.y); o[2] = f2b(v0.z); o[3] = f2b(v0.w);
    o[4] = f2b(v1.x); o[5] = f2b(v1.y); o[6] = f2b(v1.z); o[7] = f2b(v1.w);
  }
  *(ushort8_t*)(X2 + i) = o;
}

// ---- fused attention-projection kernel over att rows.
// Computes T[128 x NP] = att_bf[row0..row0+127][0:512] * Wp^T (Wp: [NP][512]).
// MODE 0: dual score epilogue -> s0,s1 (uses bias bvec, Wd, ah0, ah1).
// MODE 1: store av (+bias) as bf16 -> av_out[row][0..195].
template<int MODE>
__global__ __launch_bounds__(256)
void av_fused(const unsigned short* __restrict__ A,
              const unsigned short* __restrict__ Wp,
              const float* __restrict__ bvec,
              const float* __restrict__ Wd,
              const float* __restrict__ ah0, const float* __restrict__ ah1,
              float* __restrict__ s0, float* __restrict__ s1,
              unsigned short* __restrict__ av_out)
{
  constexpr int LDP = 40;
  __shared__ unsigned short As[128 * LDP];
  __shared__ unsigned short Bs[NP * LDP];
  __shared__ float wds[NP], bas[NP];
  __shared__ float ahAs[128], ahBs[128];
  __shared__ float sbA[128], sbB[128];

  const int tid = threadIdx.x;
  const int lane = tid & 63, wid = tid >> 6;
  const int wr = wid >> 1, wc = wid & 1;
  const int fr = lane & 15, q = lane >> 4, kg = q * 8;
  const long row0 = (long)blockIdx.x * 128;

  if (tid < NP) {
    bas[tid] = (tid < An) ? bvec[tid] : 0.f;
    if (MODE == 0) wds[tid] = (tid < An) ? Wd[tid] : 0.f;
  }
  if (MODE == 0 && tid < 128) {
    ahAs[tid] = ah0[row0 + tid];
    ahBs[tid] = ah1[row0 + tid];
  }

  f32x4 acc[4][7] = {};

  const unsigned short* Ap = A + (row0 + (tid >> 1)) * 512 + (tid & 1) * 16;
  const unsigned short* Bp = Wp + (long)tid * 512;
  const bool bload = tid < NP;
  ushort8_t pa0 = *(const ushort8_t*)Ap;
  ushort8_t pa1 = *(const ushort8_t*)(Ap + 8);
  ushort8_t pb0{}, pb1{}, pb2{}, pb3{};
  if (bload) {
    pb0 = *(const ushort8_t*)(Bp);
    pb1 = *(const ushort8_t*)(Bp + 8);
    pb2 = *(const ushort8_t*)(Bp + 16);
    pb3 = *(const ushort8_t*)(Bp + 24);
  }
  const int swA = (tid >> 1) * LDP + (tid & 1) * 16;
  const int swB = tid * LDP;

  for (int kt = 0; kt < 512; kt += 32) {
    *(ushort8_t*)&As[swA] = pa0;
    *(ushort8_t*)&As[swA + 8] = pa1;
    if (bload) {
      *(ushort8_t*)&Bs[swB] = pb0;
      *(ushort8_t*)&Bs[swB + 8] = pb1;
      *(ushort8_t*)&Bs[swB + 16] = pb2;
      *(ushort8_t*)&Bs[swB + 24] = pb3;
    }
    if (kt + 32 < 512) {
      pa0 = *(const ushort8_t*)(Ap + kt + 32);
      pa1 = *(const ushort8_t*)(Ap + kt + 40);
      if (bload) {
        pb0 = *(const ushort8_t*)(Bp + kt + 32);
        pb1 = *(const ushort8_t*)(Bp + kt + 40);
        pb2 = *(const ushort8_t*)(Bp + kt + 48);
        pb3 = *(const ushort8_t*)(Bp + kt + 56);
      }
    }
    __syncthreads();
    bf16x8 af[4], bfr[7];
#pragma unroll
    for (int m = 0; m < 4; ++m)
      af[m] = *(const bf16x8*)&As[(wr * 64 + m * 16 + fr) * LDP + kg];
#pragma unroll
    for (int n = 0; n < 7; ++n)
      bfr[n] = *(const bf16x8*)&Bs[(wc * 112 + n * 16 + fr) * LDP + kg];
#pragma unroll
    for (int m = 0; m < 4; ++m)
#pragma unroll
      for (int n = 0; n < 7; ++n)
        acc[m][n] = __builtin_amdgcn_mfma_f32_16x16x32_bf16(af[m], bfr[n], acc[m][n], 0, 0, 0);
    __syncthreads();
  }

  if (MODE == 1) {
#pragma unroll
    for (int n = 0; n < 7; ++n) {
      const int col = wc * 112 + n * 16 + fr;
      if (col >= An) continue;
      const float bv = bas[col];
#pragma unroll
      for (int m = 0; m < 4; ++m) {
#pragma unroll
        for (int j = 0; j < 4; ++j) {
          const long row = row0 + wr * 64 + m * 16 + q * 4 + j;
          av_out[row * An + col] = f2b(acc[m][n][j] + bv);
        }
      }
    }
    return;
  }

  // MODE 0: dual score reduce
  float pA[4][4], pB[4][4];
#pragma unroll
  for (int m = 0; m < 4; ++m)
#pragma unroll
    for (int j = 0; j < 4; ++j) { pA[m][j] = 0.f; pB[m][j] = 0.f; }

#pragma unroll
  for (int n = 0; n < 7; ++n) {
    const int col = wc * 112 + n * 16 + fr;
    const float wd = wds[col];
    const float bv = bas[col];
#pragma unroll
    for (int m = 0; m < 4; ++m) {
#pragma unroll
      for (int j = 0; j < 4; ++j) {
        const int rl = wr * 64 + m * 16 + q * 4 + j;
        const float av = acc[m][n][j] + bv;
        pA[m][j] += wd * tanhf_fast(av + ahAs[rl]);
        pB[m][j] += wd * tanhf_fast(av + ahBs[rl]);
      }
    }
  }
#pragma unroll
  for (int m = 0; m < 4; ++m)
#pragma unroll
    for (int j = 0; j < 4; ++j) {
#pragma unroll
      for (int off = 1; off < 16; off <<= 1) {
        pA[m][j] += __shfl_xor(pA[m][j], off);
        pB[m][j] += __shfl_xor(pB[m][j], off);
      }
    }
  __syncthreads();
  if (fr == 0 && wc == 0) {
#pragma unroll
    for (int m = 0; m < 4; ++m)
#pragma unroll
      for (int j = 0; j < 4; ++j) {
        const int rl = wr * 64 + m * 16 + q * 4 + j;
        sbA[rl] = pA[m][j]; sbB[rl] = pB[m][j];
      }
  }
  __syncthreads();
  if (fr == 0 && wc == 1) {
#pragma unroll
    for (int m = 0; m < 4; ++m)
#pragma unroll
      for (int j = 0; j < 4; ++j) {
        const int rl = wr * 64 + m * 16 + q * 4 + j;
        sbA[rl] += pA[m][j]; sbB[rl] += pB[m][j];
      }
  }
  __syncthreads();
  if (tid < 128) {
    s0[row0 + tid] = sbA[tid];
    s1[row0 + tid] = sbB[tid];
  }
}

// ---- bf16 MFMA GEMM: C[M,N] = A[M,K] * B[N,K]^T + bias[n], C f32
__global__ __launch_bounds__(256)
void gemm_bf(const unsigned short* __restrict__ A, const unsigned short* __restrict__ Bm,
             const float* __restrict__ bias, float* __restrict__ C,
             int N, int K, int ldc)
{
  constexpr int LDP = 40;
  __shared__ unsigned short As[128 * LDP];
  __shared__ unsigned short Bs[128 * LDP];
  const int tid = threadIdx.x;
  const long row0 = (long)blockIdx.y * 128;
  const int col0 = blockIdx.x * 128;
  const int wid = tid >> 6, lane = tid & 63;
  const int wr = wid >> 1, wc = wid & 1;
  const int fr = lane & 15, kg = (lane >> 4) * 8;

  f32x4 acc[4][4] = {};

  const int srow = tid >> 1;
  const int skh = tid & 1;
  const unsigned short* Ap = A + (row0 + srow) * (long)K + skh * 16;
  const int bcol = col0 + srow;
  const unsigned short* Bp = Bm + (long)(bcol < N ? bcol : N - 1) * K + skh * 16;

  ushort8_t a0 = *(const ushort8_t*)(Ap);
  ushort8_t a1 = *(const ushort8_t*)(Ap + 8);
  ushort8_t b0 = *(const ushort8_t*)(Bp);
  ushort8_t b1 = *(const ushort8_t*)(Bp + 8);

  const int sw = srow * LDP + skh * 16;
  for (int kt = 0; kt < K; kt += 32) {
    *(ushort8_t*)&As[sw] = a0;
    *(ushort8_t*)&As[sw + 8] = a1;
    *(ushort8_t*)&Bs[sw] = b0;
    *(ushort8_t*)&Bs[sw + 8] = b1;
    if (kt + 32 < K) {
      a0 = *(const ushort8_t*)(Ap + kt + 32);
      a1 = *(const ushort8_t*)(Ap + kt + 40);
      b0 = *(const ushort8_t*)(Bp + kt + 32);
      b1 = *(const ushort8_t*)(Bp + kt + 40);
    }
    __syncthreads();
    bf16x8 af[4], bfr[4];
#pragma unroll
    for (int m = 0; m < 4; ++m)
      af[m] = *(const bf16x8*)&As[(wr * 64 + m * 16 + fr) * LDP + kg];
#pragma unroll
    for (int n = 0; n < 4; ++n)
      bfr[n] = *(const bf16x8*)&Bs[(wc * 64 + n * 16 + fr) * LDP + kg];
#pragma unroll
    for (int m = 0; m < 4; ++m)
#pragma unroll
      for (int n = 0; n < 4; ++n)
        acc[m][n] = __builtin_amdgcn_mfma_f32_16x16x32_bf16(af[m], bfr[n], acc[m][n], 0, 0, 0);
    __syncthreads();
  }

  const int crow = wr * 64 + (lane >> 4) * 4;
  const int ccol = wc * 64 + fr;
#pragma unroll
  for (int n = 0; n < 4; ++n) {
    const int col = col0 + ccol + n * 16;
    if (col >= N) continue;
    const float bv = bias ? bias[col] : 0.f;
#pragma unroll
    for (int m = 0; m < 4; ++m) {
      const long rb = row0 + crow + m * 16;
#pragma unroll
      for (int j = 0; j < 4; ++j)
        C[(rb + j) * (long)ldc + col] = acc[m][n][j] + bv;
    }
  }
}

// ---- single score over cached bf16 av
__global__ __launch_bounds__(256)
void score1(const unsigned short* __restrict__ av, const float* __restrict__ ah,
            const float* __restrict__ Wd, float* __restrict__ s0)
{
  const int row = blockIdx.x * 4 + (threadIdx.x >> 6);
  const int lane = threadIdx.x & 63;
  const unsigned short* avp = av + (long)row * An;
  const float A0 = ah[row];
  float v0 = 0.f;
  for (int a = lane; a < An; a += 64)
    v0 += Wd[a] * tanhf_fast(b2f(avp[a]) + A0);
#pragma unroll
  for (int o = 32; o; o >>= 1) v0 += __shfl_down(v0, o);
  if (lane == 0) s0[row] = v0;
}

__global__ __launch_bounds__(256)
void softmax_rows(float* __restrict__ sc)
{
  const int b = blockIdx.x;
  const int t = threadIdx.x;
  float x = (t < An) ? sc[(long)b * An + t] : -3.0e38f;
  float m = x;
#pragma unroll
  for (int o = 32; o > 0; o >>= 1) m = fmaxf(m, __shfl_down(m, o));
  __shared__ float red[4];
  __shared__ float bmax, bsumv;
  const int wid = t >> 6;
  if ((t & 63) == 0) red[wid] = m;
  __syncthreads();
  if (t == 0) bmax = fmaxf(fmaxf(red[0], red[1]), fmaxf(red[2], red[3]));
  __syncthreads();
  float e = (t < An) ? __expf(x - bmax) : 0.f;
  float sm = e;
#pragma unroll
  for (int o = 32; o > 0; o >>= 1) sm += __shfl_down(sm, o);
  if ((t & 63) == 0) red[wid] = sm;
  __syncthreads();
  if (t == 0) bsumv = red[0] + red[1] + red[2] + red[3];
  __syncthreads();
  if (t < An) sc[(long)b * An + t] = e / bsumv;
}

// ---- weighted sum over bf16 att; 2 batches per block, 4 r-cols per thread
template<bool DUAL>
__global__ __launch_bounds__(256)
void wsum2(const unsigned short* __restrict__ att,
           const float* __restrict__ w0, const float* __restrict__ w1,
           const float* __restrict__ add0,
           float* __restrict__ o0, float* __restrict__ o1)
{
  const int half = threadIdx.x >> 7;
  const int b = blockIdx.x * 2 + half;
  const int t = threadIdx.x & 127;
  __shared__ float ws0[2][An], ws1[2][An];
  for (int s = t; s < An; s += 128) {
    ws0[half][s] = w0[(long)b * An + s];
    if (DUAL) ws1[half][s] = w1[(long)b * An + s];
  }
  __syncthreads();
  const unsigned short* ap = att + (long)b * An * Rn + t * 4;
  float a00 = 0, a01 = 0, a02 = 0, a03 = 0;
  float a10 = 0, a11 = 0, a12 = 0, a13 = 0;
  for (int s = 0; s < An; ++s) {
    ushort4 u = *(const ushort4*)(ap + (long)s * Rn);
    const float f0 = b2f(u.x), f1 = b2f(u.y), f2 = b2f(u.z), f3 = b2f(u.w);
    const float v0 = ws0[half][s];
    a00 = fmaf(f0, v0, a00); a01 = fmaf(f1, v0, a01);
    a02 = fmaf(f2, v0, a02); a03 = fmaf(f3, v0, a03);
    if (DUAL) {
      const float v1 = ws1[half][s];
      a10 = fmaf(f0, v1, a10); a11 = fmaf(f1, v1, a11);
      a12 = fmaf(f2, v1, a12); a13 = fmaf(f3, v1, a13);
    }
  }
  const long base = (long)b * Rn + t * 4;
  if (add0) {
    float4 ad = *(const float4*)(add0 + base);
    a00 += ad.x; a01 += ad.y; a02 += ad.z; a03 += ad.w;
  }
  float4 r0 = make_float4(a00, a01, a02, a03);
  *(float4*)(o0 + base) = r0;
  if (DUAL) *(float4*)(o1 + base) = make_float4(a10, a11, a12, a13);
}

// ---- LSTM pointwise over P=4 parallels
__global__ __launch_bounds__(256)
void gates_pw(const float* __restrict__ sums, const float* __restrict__ prev_c,
              float* __restrict__ out_c, float* __restrict__ nh,
              unsigned short* __restrict__ nh_bf)
{
  const int i = blockIdx.x * 256 + threadIdx.x;
  const int b = i >> 9;
  const int r = i & 511;
  const float c = prev_c[i];
  float aC = 0.f, aH = 0.f;
#pragma unroll
  for (int p = 0; p < 4; ++p) {
    const float* sp = sums + (long)b * Gn + p * 2048 + r;
    const float ig = sigmf(sp[0]);
    const float fg = sigmf(sp[512]);
    const float og = sigmf(sp[1024]);
    const float it = tanhf_fast(sp[1536]);
    const float nc = fmaf(fg, c, ig * it);
    aC += nc;
    aH = fmaf(og, tanhf_fast(nc), aH);
  }
  out_c[i] = aC * 0.25f;
  const float hv = aH * 0.25f;
  nh[i] = hv;
  nh_bf[i] = f2b(hv);
}

__global__ __launch_bounds__(256)
void bias3(const float* __restrict__ a, const float* __restrict__ b,
           const float* __restrict__ c, float* __restrict__ o, int n)
{
  const int i = blockIdx.x * 256 + threadIdx.x;
  if (i < n) o[i] = a[i] + b[i] + c[i];
}

} // namespace

extern "C" void kernel_launch(void* const* d_in, const int* in_sizes, int n_in,
                              void* d_out, int out_size, void* d_ws, size_t ws_size,
                              hipStream_t stream)
{
  const float* x      = (const float*)d_in[0];
  const float* att    = (const float*)d_in[1];
  const float* inputs = (const float*)d_in[2];
  const float* Wa2a   = (const float*)d_in[3];
  const float* ba2a   = (const float*)d_in[4];
  const float* Wh2a   = (const float*)d_in[5];
  const float* bh2a   = (const float*)d_in[6];
  const float* Wd2d   = (const float*)d_in[7];
  const float* Wa2a1  = (const float*)d_in[9];
  const float* ba2a1  = (const float*)d_in[10];
  const float* Wh2a1  = (const float*)d_in[11];
  const float* bh2a1  = (const float*)d_in[12];
  const float* Wd2d1  = (const float*)d_in[13];
  const float* Wi2h   = (const float*)d_in[15];
  const float* bi2h   = (const float*)d_in[16];
  const float* Wh2h   = (const float*)d_in[17];
  const float* bh2h   = (const float*)d_in[18];
  const float* Wa2h   = (const float*)d_in[19];
  const float* ba2h   = (const float*)d_in[20];
  (void)in_sizes; (void)n_in; (void)out_size; (void)ws_size;

  float* out = (float*)d_out;
  const float* prev_c0 = inputs + 0 * (long)Bn * Rn;
  const float* prev_h0 = inputs + 1 * (long)Bn * Rn;
  const float* prev_c1 = inputs + 2 * (long)Bn * Rn;
  const float* prev_h1 = inputs + 3 * (long)Bn * Rn;

  char* wsp = (char*)d_ws;
  size_t off = 0;
  auto alloc = [&](size_t bytes) -> void* {
    void* p = wsp + off;
    off += (bytes + 1023) & ~(size_t)1023;
    return p;
  };
  unsigned short* att_bf  = (unsigned short*)alloc(ROWS * Rn * 2);
  unsigned short* W2      = (unsigned short*)alloc((size_t)Gn * Kcat * 2);
  unsigned short* Wpad    = (unsigned short*)alloc((size_t)2 * NP * Rn * 2);
  unsigned short* wh2a_bf = (unsigned short*)alloc((size_t)An * Rn * 2);
  unsigned short* wh2a1_bf= (unsigned short*)alloc((size_t)An * Rn * 2);
  unsigned short* h0_bf   = (unsigned short*)alloc((size_t)Bn * Rn * 2);
  unsigned short* h1_bf   = (unsigned short*)alloc((size_t)Bn * Rn * 2);
  unsigned short* nh_bf   = (unsigned short*)alloc((size_t)Bn * Rn * 2);
  unsigned short* X2      = (unsigned short*)alloc((size_t)Bn * Kcat * 2);
  unsigned short* av1_bf  = (unsigned short*)alloc(ROWS * An * 2);
  float* ahA  = (float*)alloc(ROWS * 4);
  float* ahB  = (float*)alloc(ROWS * 4);
  float* ah1  = (float*)alloc(ROWS * 4);
  float* scA  = (float*)alloc(ROWS * 4);
  float* scB  = (float*)alloc(ROWS * 4);
  float* sc1  = (float*)alloc(ROWS * 4);
  float* res0 = (float*)alloc((size_t)Bn * Rn * 4);
  float* res1 = (float*)alloc((size_t)Bn * Rn * 4);
  float* nh   = (float*)alloc((size_t)Bn * Rn * 4);
  float* bsum = (float*)alloc((size_t)Gn * 4);
  float* sums = (float*)alloc((size_t)Bn * Gn * 4);

  const dim3 blk(256);
  unsigned short* Wpad0 = Wpad;
  unsigned short* Wpad1 = Wpad + (size_t)NP * Rn;

  // ---- conversions / packs
  f2b_copy<<<dim3(50176), blk, 0, stream>>>(att, att_bf, ROWS * Rn);
  pack_wpad<<<dim3(112), blk, 0, stream>>>(Wa2a, Wa2a1, Wpad);
  f2b_copy<<<dim3(49), blk, 0, stream>>>(Wh2a,  wh2a_bf,  (long)An * Rn);
  f2b_copy<<<dim3(49), blk, 0, stream>>>(Wh2a1, wh2a1_bf, (long)An * Rn);
  f2b_copy<<<dim3(256), blk, 0, stream>>>(prev_h0, h0_bf, (long)Bn * Rn);
  f2b_copy<<<dim3(256), blk, 0, stream>>>(prev_h1, h1_bf, (long)Bn * Rn);
  pack_w<<<dim3(6144), blk, 0, stream>>>(Wi2h, Wh2h, Wa2h, W2);
  bias3<<<dim3(Gn / 256), blk, 0, stream>>>(bi2h, bh2h, ba2h, bsum, Gn);

  // ---- ah projections for both layers' first attends
  gemm_bf<<<dim3(2, Bn / 128), blk, 0, stream>>>(h0_bf, wh2a_bf, bh2a, ahA, An, Rn, An);
  gemm_bf<<<dim3(2, Bn / 128), blk, 0, stream>>>(h1_bf, wh2a_bf, bh2a, ahB, An, Rn, An);

  // ---- fused first attends: av0 GEMM + dual score in one pass
  av_fused<0><<<dim3(ROWS / 128), blk, 0, stream>>>(
      att_bf, Wpad0, ba2a, Wd2d, ahA, ahB, scA, scB, (unsigned short*)nullptr);
  softmax_rows<<<dim3(Bn), blk, 0, stream>>>(scA);
  softmax_rows<<<dim3(Bn), blk, 0, stream>>>(scB);
  wsum2<true><<<dim3(Bn / 2), blk, 0, stream>>>(att_bf, scA, scB, (const float*)nullptr, res0, res1);

  // ---- av1 (shared by both second attends), cached bf16 (+bias)
  av_fused<1><<<dim3(ROWS / 128), blk, 0, stream>>>(
      att_bf, Wpad1, ba2a1, (const float*)nullptr, (const float*)nullptr,
      (const float*)nullptr, (float*)nullptr, (float*)nullptr, av1_bf);

  // ---- layer 0 LSTM
  pack_x<<<dim3(768), blk, 0, stream>>>(x, (const float*)nullptr, prev_h0, res0, X2);
  gemm_bf<<<dim3(Gn / 128, Bn / 128), blk, 0, stream>>>(X2, W2, bsum, sums, Gn, Kcat, Gn);
  gates_pw<<<dim3(Bn * Rn / 256), blk, 0, stream>>>(sums, prev_c0, out + 0, nh, nh_bf);

  // ---- layer 0 second attend -> top_h0
  gemm_bf<<<dim3(2, Bn / 128), blk, 0, stream>>>(nh_bf, wh2a1_bf, bh2a1, ah1, An, Rn, An);
  score1<<<dim3((int)(ROWS / 4)), blk, 0, stream>>>(av1_bf, ah1, Wd2d1, sc1);
  softmax_rows<<<dim3(Bn), blk, 0, stream>>>(sc1);
  wsum2<false><<<dim3(Bn / 2), blk, 0, stream>>>(att_bf, sc1, (const float*)nullptr, nh,
                                                 out + (long)Bn * Rn, (float*)nullptr);

  // ---- layer 1 LSTM (xt = x + top_h0)
  pack_x<<<dim3(768), blk, 0, stream>>>(x, out + (long)Bn * Rn, prev_h1, res1, X2);
  gemm_bf<<<dim3(Gn / 128, Bn / 128), blk, 0, stream>>>(X2, W2, bsum, sums, Gn, Kcat, Gn);
  gates_pw<<<dim3(Bn * Rn / 256), blk, 0, stream>>>(sums, prev_c1, out + 2 * (long)Bn * Rn, nh, nh_bf);

  // ---- layer 1 second attend -> top_h1
  gemm_bf<<<dim3(2, Bn / 128), blk, 0, stream>>>(nh_bf, wh2a1_bf, bh2a1, ah1, An, Rn, An);
  score1<<<dim3((int)(ROWS / 4)), blk, 0, stream>>>(av1_bf, ah1, Wd2d1, sc1);
  softmax_rows<<<dim3(Bn), blk, 0, stream>>>(sc1);
  wsum2<false><<<dim3(Bn / 2), blk, 0, stream>>>(att_bf, sc1, (const float*)nullptr, nh,
                                                 out + 3 * (long)Bn * Rn, (float*)nullptr);
}

// Round 4
// 737.386 us; speedup vs baseline: 6.3322x; 1.0494x over previous
//
#include <hip/hip_runtime.h>
#include <math.h>

typedef __attribute__((ext_vector_type(8))) unsigned short ushort8_t;
typedef __attribute__((ext_vector_type(8))) short bf16x8;
typedef __attribute__((ext_vector_type(4))) float f32x4;

namespace {

constexpr int Bn = 1024;
constexpr int Rn = 512;
constexpr int An = 196;
constexpr int Gn = 8192;     // P*4R
constexpr int Kcat = 1536;   // 3*R
constexpr int NP = 224;      // padded att cols per set (14 frags)
constexpr long ROWS = (long)Bn * An;  // 200704

__device__ __forceinline__ float b2f(unsigned short u) {
  union { unsigned int i; float f; } v; v.i = ((unsigned int)u) << 16; return v.f;
}
__device__ __forceinline__ unsigned short f2b(float f) {
  union { float f; unsigned int i; } v; v.f = f;
  unsigned int r = v.i + 0x7fffu + ((v.i >> 16) & 1u);
  return (unsigned short)(r >> 16);
}
__device__ __forceinline__ float sigmf(float x) {
  return __builtin_amdgcn_rcpf(1.f + __expf(-x));
}
__device__ __forceinline__ float tanhf_fast(float x) {
  const float e = __expf(2.f * x);
  return 1.f - 2.f * __builtin_amdgcn_rcpf(e + 1.f);
}

// ---- f32 -> bf16 copy, 8 elems/thread
__global__ __launch_bounds__(256)
void f2b_copy(const float* __restrict__ src, unsigned short* __restrict__ dst, long n)
{
  long i = ((long)blockIdx.x * 256 + threadIdx.x) * 8;
  const long stride = (long)gridDim.x * 256 * 8;
  for (; i + 8 <= n; i += stride) {
    float4 a = *(const float4*)(src + i);
    float4 b = *(const float4*)(src + i + 4);
    ushort8_t o;
    o[0] = f2b(a.x); o[1] = f2b(a.y); o[2] = f2b(a.z); o[3] = f2b(a.w);
    o[4] = f2b(b.x); o[5] = f2b(b.y); o[6] = f2b(b.z); o[7] = f2b(b.w);
    *(ushort8_t*)(dst + i) = o;
  }
}

// ---- pad+convert attention weights: Wp[2][NP][512] from Wa0/Wa1 [196][512]
__global__ __launch_bounds__(256)
void pack_wpad(const float* __restrict__ Wa0, const float* __restrict__ Wa1,
               unsigned short* __restrict__ Wp)
{
  long i = ((long)blockIdx.x * 256 + threadIdx.x) * 8;
  if (i >= 2L * NP * 512) return;
  const int set = (int)(i / (NP * 512));
  const int rem = (int)(i % (NP * 512));
  const int row = rem / 512, k = rem % 512;
  ushort8_t o;
  if (row < An) {
    const float* s = (set ? Wa1 : Wa0) + (long)row * 512 + k;
    float4 a = *(const float4*)s, b = *(const float4*)(s + 4);
    o[0] = f2b(a.x); o[1] = f2b(a.y); o[2] = f2b(a.z); o[3] = f2b(a.w);
    o[4] = f2b(b.x); o[5] = f2b(b.y); o[6] = f2b(b.z); o[7] = f2b(b.w);
  } else {
    o = ushort8_t{0,0,0,0,0,0,0,0};
  }
  *(ushort8_t*)(Wp + i) = o;
}

// ---- concat gate weights [8192][1536] bf16: [Wi | Wh | Wa]
__global__ __launch_bounds__(256)
void pack_w(const float* __restrict__ Wi, const float* __restrict__ Wh,
            const float* __restrict__ Wa, unsigned short* __restrict__ W2)
{
  long i = ((long)blockIdx.x * 256 + threadIdx.x) * 8;
  if (i >= (long)Gn * Kcat) return;
  const int g = (int)(i / Kcat);
  const int k = (int)(i % Kcat);
  const float* src = (k < 512) ? Wi + (long)g * 512 + k
                   : (k < 1024) ? Wh + (long)g * 512 + (k - 512)
                   : Wa + (long)g * 512 + (k - 1024);
  float4 a = *(const float4*)src;
  float4 b = *(const float4*)(src + 4);
  ushort8_t o;
  o[0] = f2b(a.x); o[1] = f2b(a.y); o[2] = f2b(a.z); o[3] = f2b(a.w);
  o[4] = f2b(b.x); o[5] = f2b(b.y); o[6] = f2b(b.z); o[7] = f2b(b.w);
  *(ushort8_t*)(W2 + i) = o;
}

// ---- concat gate inputs [1024][1536] bf16: [xa(+xb) | h | a]
__global__ __launch_bounds__(256)
void pack_x(const float* __restrict__ xa, const float* __restrict__ xb,
            const float* __restrict__ h, const float* __restrict__ a,
            unsigned short* __restrict__ X2)
{
  long i = ((long)blockIdx.x * 256 + threadIdx.x) * 8;
  if (i >= (long)Bn * Kcat) return;
  const int b = (int)(i / Kcat);
  const int k = (int)(i % Kcat);
  ushort8_t o;
  if (k < 512) {
    const float* s = xa + (long)b * 512 + k;
    float4 v0 = *(const float4*)s, v1 = *(const float4*)(s + 4);
    if (xb) {
      const float* s2 = xb + (long)b * 512 + k;
      float4 w0 = *(const float4*)s2, w1 = *(const float4*)(s2 + 4);
      v0.x += w0.x; v0.y += w0.y; v0.z += w0.z; v0.w += w0.w;
      v1.x += w1.x; v1.y += w1.y; v1.z += w1.z; v1.w += w1.w;
    }
    o[0] = f2b(v0.x); o[1] = f2b(v0.y); o[2] = f2b(v0.z); o[3] = f2b(v0.w);
    o[4] = f2b(v1.x); o[5] = f2b(v1.y); o[6] = f2b(v1.z); o[7] = f2b(v1.w);
  } else {
    const float* s = (k < 1024) ? h + (long)b * 512 + (k - 512)
                                : a + (long)b * 512 + (k - 1024);
    float4 v0 = *(const float4*)s, v1 = *(const float4*)(s + 4);
    o[0] = f2b(v0.x); o[1] = f2b(v0.y); o[2] = f2b(v0.z); o[3] = f2b(v0.w);
    o[4] = f2b(v1.x); o[5] = f2b(v1.y); o[6] = f2b(v1.z); o[7] = f2b(v1.w);
  }
  *(ushort8_t*)(X2 + i) = o;
}

// ---- mega attention-projection kernel.
// Per 128-row tile of att (f32 input):
//   - converts+writes att_bf (side product)
//   - computes T[128 x 448] = att * [Wa2a_pad | Wa2a1_pad]^T via MFMA
//   - waves wc<2 (cols 0..223 = set0): dual first-attend score -> s0, s1
//   - waves wc>=2 (cols 224..447 = set1): av1(+bias) -> av_out bf16
__global__ __launch_bounds__(512)
void av_all(const float* __restrict__ A32,
            unsigned short* __restrict__ att_out,
            const unsigned short* __restrict__ Wcat,
            const float* __restrict__ b0vec, const float* __restrict__ b1vec,
            const float* __restrict__ Wd,
            const float* __restrict__ ah0, const float* __restrict__ ah1,
            float* __restrict__ s0, float* __restrict__ s1,
            unsigned short* __restrict__ av_out)
{
  constexpr int LDP = 40;
  __shared__ unsigned short As[128 * LDP];
  __shared__ unsigned short Bs[448 * LDP];
  __shared__ float wds[NP], bas0[NP], bas1[NP];
  __shared__ float ahAs[128], ahBs[128];
  __shared__ float sbA[128], sbB[128];

  const int tid = threadIdx.x;
  const int lane = tid & 63, wid = tid >> 6;
  const int wr = wid >> 2, wc = wid & 3;          // 2 x 4 wave grid
  const int fr = lane & 15, q = lane >> 4, kg = q * 8;
  const long row0 = (long)blockIdx.x * 128;

  if (tid < NP) {
    bas0[tid] = (tid < An) ? b0vec[tid] : 0.f;
    bas1[tid] = (tid < An) ? b1vec[tid] : 0.f;
    wds[tid]  = (tid < An) ? Wd[tid] : 0.f;
  }
  if (tid >= 256 && tid < 384) {
    ahAs[tid - 256] = ah0[row0 + tid - 256];
    ahBs[tid - 256] = ah1[row0 + tid - 256];
  }

  f32x4 acc[4][7] = {};

  // A staging: thread t handles row t>>2, k-chunk (t&3)*8 (f32 -> bf16)
  const int arow = tid >> 2, akc = (tid & 3) * 8;
  const float* Ap = A32 + (row0 + arow) * 512 + akc;
  unsigned short* Aout = att_out + (row0 + arow) * 512 + akc;
  // B staging: thread t<448 handles weight row t, 32 k per step
  const bool bload = tid < 448;
  const unsigned short* Bp = Wcat + (long)tid * 512;

  float4 fa0 = *(const float4*)Ap;
  float4 fa1 = *(const float4*)(Ap + 4);
  ushort8_t pb0{}, pb1{}, pb2{}, pb3{};
  if (bload) {
    pb0 = *(const ushort8_t*)(Bp);
    pb1 = *(const ushort8_t*)(Bp + 8);
    pb2 = *(const ushort8_t*)(Bp + 16);
    pb3 = *(const ushort8_t*)(Bp + 24);
  }
  const int swA = arow * LDP + akc;
  const int swB = tid * LDP;

  for (int kt = 0; kt < 512; kt += 32) {
    ushort8_t ua;
    ua[0] = f2b(fa0.x); ua[1] = f2b(fa0.y); ua[2] = f2b(fa0.z); ua[3] = f2b(fa0.w);
    ua[4] = f2b(fa1.x); ua[5] = f2b(fa1.y); ua[6] = f2b(fa1.z); ua[7] = f2b(fa1.w);
    *(ushort8_t*)&As[swA] = ua;
    *(ushort8_t*)(Aout + kt) = ua;
    if (bload) {
      *(ushort8_t*)&Bs[swB] = pb0;
      *(ushort8_t*)&Bs[swB + 8] = pb1;
      *(ushort8_t*)&Bs[swB + 16] = pb2;
      *(ushort8_t*)&Bs[swB + 24] = pb3;
    }
    if (kt + 32 < 512) {
      fa0 = *(const float4*)(Ap + kt + 32);
      fa1 = *(const float4*)(Ap + kt + 36);
      if (bload) {
        pb0 = *(const ushort8_t*)(Bp + kt + 32);
        pb1 = *(const ushort8_t*)(Bp + kt + 40);
        pb2 = *(const ushort8_t*)(Bp + kt + 48);
        pb3 = *(const ushort8_t*)(Bp + kt + 56);
      }
    }
    __syncthreads();
    bf16x8 af[4], bfr[7];
#pragma unroll
    for (int m = 0; m < 4; ++m)
      af[m] = *(const bf16x8*)&As[(wr * 64 + m * 16 + fr) * LDP + kg];
#pragma unroll
    for (int n = 0; n < 7; ++n)
      bfr[n] = *(const bf16x8*)&Bs[(wc * 112 + n * 16 + fr) * LDP + kg];
#pragma unroll
    for (int m = 0; m < 4; ++m)
#pragma unroll
      for (int n = 0; n < 7; ++n)
        acc[m][n] = __builtin_amdgcn_mfma_f32_16x16x32_bf16(af[m], bfr[n], acc[m][n], 0, 0, 0);
    __syncthreads();
  }

  float pA[4][4], pB[4][4];
#pragma unroll
  for (int m = 0; m < 4; ++m)
#pragma unroll
    for (int j = 0; j < 4; ++j) { pA[m][j] = 0.f; pB[m][j] = 0.f; }

  if (wc < 2) {
    // set 0: dual score partials over cols wc*112 + n*16 + fr
#pragma unroll
    for (int n = 0; n < 7; ++n) {
      const int col = wc * 112 + n * 16 + fr;
      const float wd = wds[col];
      const float bv = bas0[col];
#pragma unroll
      for (int m = 0; m < 4; ++m) {
#pragma unroll
        for (int j = 0; j < 4; ++j) {
          const int rl = wr * 64 + m * 16 + q * 4 + j;
          const float av = acc[m][n][j] + bv;
          pA[m][j] += wd * tanhf_fast(av + ahAs[rl]);
          pB[m][j] += wd * tanhf_fast(av + ahBs[rl]);
        }
      }
    }
#pragma unroll
    for (int m = 0; m < 4; ++m)
#pragma unroll
      for (int j = 0; j < 4; ++j) {
#pragma unroll
        for (int off = 1; off < 16; off <<= 1) {
          pA[m][j] += __shfl_xor(pA[m][j], off);
          pB[m][j] += __shfl_xor(pB[m][j], off);
        }
      }
  } else {
    // set 1: store av1 (+bias) bf16
#pragma unroll
    for (int n = 0; n < 7; ++n) {
      const int col1 = (wc - 2) * 112 + n * 16 + fr;
      if (col1 >= An) continue;
      const float bv = bas1[col1];
#pragma unroll
      for (int m = 0; m < 4; ++m) {
#pragma unroll
        for (int j = 0; j < 4; ++j) {
          const long row = row0 + wr * 64 + m * 16 + q * 4 + j;
          av_out[row * An + col1] = f2b(acc[m][n][j] + bv);
        }
      }
    }
  }
  __syncthreads();
  if (wc == 0 && fr == 0) {
#pragma unroll
    for (int m = 0; m < 4; ++m)
#pragma unroll
      for (int j = 0; j < 4; ++j) {
        const int rl = wr * 64 + m * 16 + q * 4 + j;
        sbA[rl] = pA[m][j]; sbB[rl] = pB[m][j];
      }
  }
  __syncthreads();
  if (wc == 1 && fr == 0) {
#pragma unroll
    for (int m = 0; m < 4; ++m)
#pragma unroll
      for (int j = 0; j < 4; ++j) {
        const int rl = wr * 64 + m * 16 + q * 4 + j;
        sbA[rl] += pA[m][j]; sbB[rl] += pB[m][j];
      }
  }
  __syncthreads();
  if (tid < 128) {
    s0[row0 + tid] = sbA[tid];
    s1[row0 + tid] = sbB[tid];
  }
}

// ---- bf16 MFMA GEMM: C[M,N] = A[M,K] * B[N,K]^T + bias[n], C f32
__global__ __launch_bounds__(256)
void gemm_bf(const unsigned short* __restrict__ A, const unsigned short* __restrict__ Bm,
             const float* __restrict__ bias, float* __restrict__ C,
             int N, int K, int ldc)
{
  constexpr int LDP = 40;
  __shared__ unsigned short As[128 * LDP];
  __shared__ unsigned short Bs[128 * LDP];
  const int tid = threadIdx.x;
  const long row0 = (long)blockIdx.y * 128;
  const int col0 = blockIdx.x * 128;
  const int wid = tid >> 6, lane = tid & 63;
  const int wr = wid >> 1, wc = wid & 1;
  const int fr = lane & 15, kg = (lane >> 4) * 8;

  f32x4 acc[4][4] = {};

  const int srow = tid >> 1;
  const int skh = tid & 1;
  const unsigned short* Ap = A + (row0 + srow) * (long)K + skh * 16;
  const int bcol = col0 + srow;
  const unsigned short* Bp = Bm + (long)(bcol < N ? bcol : N - 1) * K + skh * 16;

  ushort8_t a0 = *(const ushort8_t*)(Ap);
  ushort8_t a1 = *(const ushort8_t*)(Ap + 8);
  ushort8_t b0 = *(const ushort8_t*)(Bp);
  ushort8_t b1 = *(const ushort8_t*)(Bp + 8);

  const int sw = srow * LDP + skh * 16;
  for (int kt = 0; kt < K; kt += 32) {
    *(ushort8_t*)&As[sw] = a0;
    *(ushort8_t*)&As[sw + 8] = a1;
    *(ushort8_t*)&Bs[sw] = b0;
    *(ushort8_t*)&Bs[sw + 8] = b1;
    if (kt + 32 < K) {
      a0 = *(const ushort8_t*)(Ap + kt + 32);
      a1 = *(const ushort8_t*)(Ap + kt + 40);
      b0 = *(const ushort8_t*)(Bp + kt + 32);
      b1 = *(const ushort8_t*)(Bp + kt + 40);
    }
    __syncthreads();
    bf16x8 af[4], bfr[4];
#pragma unroll
    for (int m = 0; m < 4; ++m)
      af[m] = *(const bf16x8*)&As[(wr * 64 + m * 16 + fr) * LDP + kg];
#pragma unroll
    for (int n = 0; n < 4; ++n)
      bfr[n] = *(const bf16x8*)&Bs[(wc * 64 + n * 16 + fr) * LDP + kg];
#pragma unroll
    for (int m = 0; m < 4; ++m)
#pragma unroll
      for (int n = 0; n < 4; ++n)
        acc[m][n] = __builtin_amdgcn_mfma_f32_16x16x32_bf16(af[m], bfr[n], acc[m][n], 0, 0, 0);
    __syncthreads();
  }

  const int crow = wr * 64 + (lane >> 4) * 4;
  const int ccol = wc * 64 + fr;
#pragma unroll
  for (int n = 0; n < 4; ++n) {
    const int col = col0 + ccol + n * 16;
    if (col >= N) continue;
    const float bv = bias ? bias[col] : 0.f;
#pragma unroll
    for (int m = 0; m < 4; ++m) {
      const long rb = row0 + crow + m * 16;
#pragma unroll
      for (int j = 0; j < 4; ++j)
        C[(rb + j) * (long)ldc + col] = acc[m][n][j] + bv;
    }
  }
}

// ---- single score over cached bf16 av
__global__ __launch_bounds__(256)
void score1(const unsigned short* __restrict__ av, const float* __restrict__ ah,
            const float* __restrict__ Wd, float* __restrict__ s0)
{
  const int row = blockIdx.x * 4 + (threadIdx.x >> 6);
  const int lane = threadIdx.x & 63;
  const unsigned short* avp = av + (long)row * An;
  const float A0 = ah[row];
  float v0 = 0.f;
  for (int a = lane; a < An; a += 64)
    v0 += Wd[a] * tanhf_fast(b2f(avp[a]) + A0);
#pragma unroll
  for (int o = 32; o; o >>= 1) v0 += __shfl_down(v0, o);
  if (lane == 0) s0[row] = v0;
}

__global__ __launch_bounds__(256)
void softmax_rows(float* __restrict__ sc)
{
  const int b = blockIdx.x;
  const int t = threadIdx.x;
  float x = (t < An) ? sc[(long)b * An + t] : -3.0e38f;
  float m = x;
#pragma unroll
  for (int o = 32; o > 0; o >>= 1) m = fmaxf(m, __shfl_down(m, o));
  __shared__ float red[4];
  __shared__ float bmax, bsumv;
  const int wid = t >> 6;
  if ((t & 63) == 0) red[wid] = m;
  __syncthreads();
  if (t == 0) bmax = fmaxf(fmaxf(red[0], red[1]), fmaxf(red[2], red[3]));
  __syncthreads();
  float e = (t < An) ? __expf(x - bmax) : 0.f;
  float sm = e;
#pragma unroll
  for (int o = 32; o > 0; o >>= 1) sm += __shfl_down(sm, o);
  if ((t & 63) == 0) red[wid] = sm;
  __syncthreads();
  if (t == 0) bsumv = red[0] + red[1] + red[2] + red[3];
  __syncthreads();
  if (t < An) sc[(long)b * An + t] = e / bsumv;
}

// ---- weighted sum over bf16 att; 2 batches per block, 4 r-cols per thread
template<bool DUAL>
__global__ __launch_bounds__(256)
void wsum2(const unsigned short* __restrict__ att,
           const float* __restrict__ w0, const float* __restrict__ w1,
           const float* __restrict__ add0,
           float* __restrict__ o0, float* __restrict__ o1)
{
  const int half = threadIdx.x >> 7;
  const int b = blockIdx.x * 2 + half;
  const int t = threadIdx.x & 127;
  __shared__ float ws0[2][An], ws1[2][An];
  for (int s = t; s < An; s += 128) {
    ws0[half][s] = w0[(long)b * An + s];
    if (DUAL) ws1[half][s] = w1[(long)b * An + s];
  }
  __syncthreads();
  const unsigned short* ap = att + (long)b * An * Rn + t * 4;
  float a00 = 0, a01 = 0, a02 = 0, a03 = 0;
  float a10 = 0, a11 = 0, a12 = 0, a13 = 0;
  for (int s = 0; s < An; ++s) {
    ushort4 u = *(const ushort4*)(ap + (long)s * Rn);
    const float f0 = b2f(u.x), f1 = b2f(u.y), f2 = b2f(u.z), f3 = b2f(u.w);
    const float v0 = ws0[half][s];
    a00 = fmaf(f0, v0, a00); a01 = fmaf(f1, v0, a01);
    a02 = fmaf(f2, v0, a02); a03 = fmaf(f3, v0, a03);
    if (DUAL) {
      const float v1 = ws1[half][s];
      a10 = fmaf(f0, v1, a10); a11 = fmaf(f1, v1, a11);
      a12 = fmaf(f2, v1, a12); a13 = fmaf(f3, v1, a13);
    }
  }
  const long base = (long)b * Rn + t * 4;
  if (add0) {
    float4 ad = *(const float4*)(add0 + base);
    a00 += ad.x; a01 += ad.y; a02 += ad.z; a03 += ad.w;
  }
  float4 r0 = make_float4(a00, a01, a02, a03);
  *(float4*)(o0 + base) = r0;
  if (DUAL) *(float4*)(o1 + base) = make_float4(a10, a11, a12, a13);
}

// ---- LSTM pointwise over P=4 parallels
__global__ __launch_bounds__(256)
void gates_pw(const float* __restrict__ sums, const float* __restrict__ prev_c,
              float* __restrict__ out_c, float* __restrict__ nh,
              unsigned short* __restrict__ nh_bf)
{
  const int i = blockIdx.x * 256 + threadIdx.x;
  const int b = i >> 9;
  const int r = i & 511;
  const float c = prev_c[i];
  float aC = 0.f, aH = 0.f;
#pragma unroll
  for (int p = 0; p < 4; ++p) {
    const float* sp = sums + (long)b * Gn + p * 2048 + r;
    const float ig = sigmf(sp[0]);
    const float fg = sigmf(sp[512]);
    const float og = sigmf(sp[1024]);
    const float it = tanhf_fast(sp[1536]);
    const float nc = fmaf(fg, c, ig * it);
    aC += nc;
    aH = fmaf(og, tanhf_fast(nc), aH);
  }
  out_c[i] = aC * 0.25f;
  const float hv = aH * 0.25f;
  nh[i] = hv;
  nh_bf[i] = f2b(hv);
}

__global__ __launch_bounds__(256)
void bias3(const float* __restrict__ a, const float* __restrict__ b,
           const float* __restrict__ c, float* __restrict__ o, int n)
{
  const int i = blockIdx.x * 256 + threadIdx.x;
  if (i < n) o[i] = a[i] + b[i] + c[i];
}

} // namespace

extern "C" void kernel_launch(void* const* d_in, const int* in_sizes, int n_in,
                              void* d_out, int out_size, void* d_ws, size_t ws_size,
                              hipStream_t stream)
{
  const float* x      = (const float*)d_in[0];
  const float* att    = (const float*)d_in[1];
  const float* inputs = (const float*)d_in[2];
  const float* Wa2a   = (const float*)d_in[3];
  const float* ba2a   = (const float*)d_in[4];
  const float* Wh2a   = (const float*)d_in[5];
  const float* bh2a   = (const float*)d_in[6];
  const float* Wd2d   = (const float*)d_in[7];
  const float* Wa2a1  = (const float*)d_in[9];
  const float* ba2a1  = (const float*)d_in[10];
  const float* Wh2a1  = (const float*)d_in[11];
  const float* bh2a1  = (const float*)d_in[12];
  const float* Wd2d1  = (const float*)d_in[13];
  const float* Wi2h   = (const float*)d_in[15];
  const float* bi2h   = (const float*)d_in[16];
  const float* Wh2h   = (const float*)d_in[17];
  const float* bh2h   = (const float*)d_in[18];
  const float* Wa2h   = (const float*)d_in[19];
  const float* ba2h   = (const float*)d_in[20];
  (void)in_sizes; (void)n_in; (void)out_size; (void)ws_size;

  float* out = (float*)d_out;
  const float* prev_c0 = inputs + 0 * (long)Bn * Rn;
  const float* prev_h0 = inputs + 1 * (long)Bn * Rn;
  const float* prev_c1 = inputs + 2 * (long)Bn * Rn;
  const float* prev_h1 = inputs + 3 * (long)Bn * Rn;

  char* wsp = (char*)d_ws;
  size_t off = 0;
  auto alloc = [&](size_t bytes) -> void* {
    void* p = wsp + off;
    off += (bytes + 1023) & ~(size_t)1023;
    return p;
  };
  unsigned short* att_bf  = (unsigned short*)alloc(ROWS * Rn * 2);
  unsigned short* W2      = (unsigned short*)alloc((size_t)Gn * Kcat * 2);
  unsigned short* Wpad    = (unsigned short*)alloc((size_t)2 * NP * Rn * 2);
  unsigned short* wh2a_bf = (unsigned short*)alloc((size_t)An * Rn * 2);
  unsigned short* wh2a1_bf= (unsigned short*)alloc((size_t)An * Rn * 2);
  unsigned short* h0_bf   = (unsigned short*)alloc((size_t)Bn * Rn * 2);
  unsigned short* h1_bf   = (unsigned short*)alloc((size_t)Bn * Rn * 2);
  unsigned short* nh_bf   = (unsigned short*)alloc((size_t)Bn * Rn * 2);
  unsigned short* X2      = (unsigned short*)alloc((size_t)Bn * Kcat * 2);
  unsigned short* av1_bf  = (unsigned short*)alloc(ROWS * An * 2);
  float* ahA  = (float*)alloc(ROWS * 4);
  float* ahB  = (float*)alloc(ROWS * 4);
  float* ah1  = (float*)alloc(ROWS * 4);
  float* scA  = (float*)alloc(ROWS * 4);
  float* scB  = (float*)alloc(ROWS * 4);
  float* sc1  = (float*)alloc(ROWS * 4);
  float* res0 = (float*)alloc((size_t)Bn * Rn * 4);
  float* res1 = (float*)alloc((size_t)Bn * Rn * 4);
  float* nh   = (float*)alloc((size_t)Bn * Rn * 4);
  float* bsum = (float*)alloc((size_t)Gn * 4);
  float* sums = (float*)alloc((size_t)Bn * Gn * 4);

  const dim3 blk(256);

  // ---- conversions / packs (small)
  pack_wpad<<<dim3(112), blk, 0, stream>>>(Wa2a, Wa2a1, Wpad);
  f2b_copy<<<dim3(49), blk, 0, stream>>>(Wh2a,  wh2a_bf,  (long)An * Rn);
  f2b_copy<<<dim3(49), blk, 0, stream>>>(Wh2a1, wh2a1_bf, (long)An * Rn);
  f2b_copy<<<dim3(256), blk, 0, stream>>>(prev_h0, h0_bf, (long)Bn * Rn);
  f2b_copy<<<dim3(256), blk, 0, stream>>>(prev_h1, h1_bf, (long)Bn * Rn);
  pack_w<<<dim3(6144), blk, 0, stream>>>(Wi2h, Wh2h, Wa2h, W2);
  bias3<<<dim3(Gn / 256), blk, 0, stream>>>(bi2h, bh2h, ba2h, bsum, Gn);

  // ---- ah projections for both layers' first attends
  gemm_bf<<<dim3(2, Bn / 128), blk, 0, stream>>>(h0_bf, wh2a_bf, bh2a, ahA, An, Rn, An);
  gemm_bf<<<dim3(2, Bn / 128), blk, 0, stream>>>(h1_bf, wh2a_bf, bh2a, ahB, An, Rn, An);

  // ---- mega pass: att f32 -> att_bf, av0+dual score, av1 cache
  av_all<<<dim3((int)(ROWS / 128)), dim3(512), 0, stream>>>(
      att, att_bf, Wpad, ba2a, ba2a1, Wd2d, ahA, ahB, scA, scB, av1_bf);
  softmax_rows<<<dim3(Bn), blk, 0, stream>>>(scA);
  softmax_rows<<<dim3(Bn), blk, 0, stream>>>(scB);
  wsum2<true><<<dim3(Bn / 2), blk, 0, stream>>>(att_bf, scA, scB, (const float*)nullptr, res0, res1);

  // ---- layer 0 LSTM
  pack_x<<<dim3(768), blk, 0, stream>>>(x, (const float*)nullptr, prev_h0, res0, X2);
  gemm_bf<<<dim3(Gn / 128, Bn / 128), blk, 0, stream>>>(X2, W2, bsum, sums, Gn, Kcat, Gn);
  gates_pw<<<dim3(Bn * Rn / 256), blk, 0, stream>>>(sums, prev_c0, out + 0, nh, nh_bf);

  // ---- layer 0 second attend -> top_h0
  gemm_bf<<<dim3(2, Bn / 128), blk, 0, stream>>>(nh_bf, wh2a1_bf, bh2a1, ah1, An, Rn, An);
  score1<<<dim3((int)(ROWS / 4)), blk, 0, stream>>>(av1_bf, ah1, Wd2d1, sc1);
  softmax_rows<<<dim3(Bn), blk, 0, stream>>>(sc1);
  wsum2<false><<<dim3(Bn / 2), blk, 0, stream>>>(att_bf, sc1, (const float*)nullptr, nh,
                                                 out + (long)Bn * Rn, (float*)nullptr);

  // ---- layer 1 LSTM (xt = x + top_h0)
  pack_x<<<dim3(768), blk, 0, stream>>>(x, out + (long)Bn * Rn, prev_h1, res1, X2);
  gemm_bf<<<dim3(Gn / 128, Bn / 128), blk, 0, stream>>>(X2, W2, bsum, sums, Gn, Kcat, Gn);
  gates_pw<<<dim3(Bn * Rn / 256), blk, 0, stream>>>(sums, prev_c1, out + 2 * (long)Bn * Rn, nh, nh_bf);

  // ---- layer 1 second attend -> top_h1
  gemm_bf<<<dim3(2, Bn / 128), blk, 0, stream>>>(nh_bf, wh2a1_bf, bh2a1, ah1, An, Rn, An);
  score1<<<dim3((int)(ROWS / 4)), blk, 0, stream>>>(av1_bf, ah1, Wd2d1, sc1);
  softmax_rows<<<dim3(Bn), blk, 0, stream>>>(sc1);
  wsum2<false><<<dim3(Bn / 2), blk, 0, stream>>>(att_bf, sc1, (const float*)nullptr, nh,
                                                 out + 3 * (long)Bn * Rn, (float*)nullptr);
}